// Round 1
// baseline (1198.601 us; speedup 1.0000x reference)
//
#include <hip/hip_runtime.h>

#define NN 50000
#define EE 800000
#define FF 128
#define HH 256
#define CC 40
#define BN_EPS 1e-5f
#define TM 32
#define EPB 8

// ---------------- init: h_a = b_edge broadcast, stats = 0 ----------------
__global__ void k_init(float* __restrict__ bufH, float* __restrict__ stats,
                       const float* __restrict__ b_edge) {
    int i = blockIdx.x * blockDim.x + threadIdx.x;
    if (i < 2 * HH) stats[i] = 0.f;
    const int total = NN * HH;
    for (int j = i; j < total; j += gridDim.x * blockDim.x)
        bufH[j] = b_edge[j & (HH - 1)];
}

// ---------------- scatter: h_a += ew[e] * W_edge[src[e]] at dst[e] ----------------
__global__ void k_scatter(const int* __restrict__ ei, const float* __restrict__ ew,
                          const float* __restrict__ W_edge, float* __restrict__ bufH) {
    __shared__ int sS[EPB], sD[EPB];
    __shared__ float sW[EPB];
    const int tid = threadIdx.x;
    const int e0 = blockIdx.x * EPB;
    if (tid < EPB) {
        sS[tid] = ei[e0 + tid];
        sD[tid] = ei[EE + e0 + tid];
        sW[tid] = ew[e0 + tid];
    }
    __syncthreads();
#pragma unroll
    for (int ee = 0; ee < EPB; ++ee) {
        float v = W_edge[(size_t)sS[ee] * HH + tid] * sW[ee];
        atomicAdd(&bufH[(size_t)sD[ee] * HH + tid], v);
    }
}

// ---------------- 8-row x 4-col register-blocked GEMM helper ----------------
template <int K>
__device__ __forceinline__ void gemm8(const float* const* Arow, const float* __restrict__ W,
                                      int c0, float4 acc[8]) {
#pragma unroll 4
    for (int k = 0; k < K; k += 4) {
        float4 a[8];
#pragma unroll
        for (int r = 0; r < 8; ++r)
            a[r] = *(const float4*)(Arow[r] + k);
        float4 w0 = *(const float4*)(W + (size_t)(k + 0) * HH + c0);
        float4 w1 = *(const float4*)(W + (size_t)(k + 1) * HH + c0);
        float4 w2 = *(const float4*)(W + (size_t)(k + 2) * HH + c0);
        float4 w3 = *(const float4*)(W + (size_t)(k + 3) * HH + c0);
#pragma unroll
        for (int r = 0; r < 8; ++r) {
            acc[r].x += a[r].x * w0.x + a[r].y * w1.x + a[r].z * w2.x + a[r].w * w3.x;
            acc[r].y += a[r].x * w0.y + a[r].y * w1.y + a[r].z * w2.y + a[r].w * w3.y;
            acc[r].z += a[r].x * w0.z + a[r].y * w1.z + a[r].z * w2.z + a[r].w * w3.z;
            acc[r].w += a[r].x * w0.w + a[r].y * w1.w + a[r].z * w2.w + a[r].w * w3.w;
        }
    }
}

// ---------------- fused dense chain + BN stats ----------------
__global__ __launch_bounds__(256)
void k_fused(float* __restrict__ bufH, const float* __restrict__ x,
             const float* __restrict__ W_node, const float* __restrict__ b_node,
             const float* __restrict__ W_c1, const float* __restrict__ b_c1,
             const float* __restrict__ W_c2, const float* __restrict__ b_c2,
             const float* __restrict__ W_f1, const float* __restrict__ b_f1,
             float* __restrict__ stats) {
    __shared__ float sHX[TM * HH];   // 32 KB
    __shared__ float sOut[TM * HH];  // 32 KB
    const int tid = threadIdx.x;
    const int tc = tid & 63, tr = tid >> 6;
    const int c0 = tc * 4;
    const int rb = tr * 8;
    const int row0 = blockIdx.x * TM;

    int rows[8];
#pragma unroll
    for (int r = 0; r < 8; ++r) {
        int g = row0 + rb + r;
        rows[r] = g < NN ? g : NN - 1;  // clamp (stores/stats guarded by true validity)
    }

    // ---- phase A: hx = x @ W_node + b_node -> sHX
    {
        float4 acc[8];
#pragma unroll
        for (int r = 0; r < 8; ++r) { acc[r].x = acc[r].y = acc[r].z = acc[r].w = 0.f; }
        const float* Arow[8];
#pragma unroll
        for (int r = 0; r < 8; ++r) Arow[r] = x + (size_t)rows[r] * FF;
        gemm8<FF>(Arow, W_node, c0, acc);
        float4 b = *(const float4*)(b_node + c0);
#pragma unroll
        for (int r = 0; r < 8; ++r) {
            float4 v;
            v.x = acc[r].x + b.x; v.y = acc[r].y + b.y;
            v.z = acc[r].z + b.z; v.w = acc[r].w + b.w;
            *(float4*)(sHX + (rb + r) * HH + c0) = v;
        }
    }
    __syncthreads();

    // ---- phase B: out = relu(ha + ha@Wc1 + bc1 + hx + hx@Wc2 + bc2) -> sOut
    {
        float4 acc[8];
#pragma unroll
        for (int r = 0; r < 8; ++r) { acc[r].x = acc[r].y = acc[r].z = acc[r].w = 0.f; }
        const float* Arow[8];
#pragma unroll
        for (int r = 0; r < 8; ++r) Arow[r] = bufH + (size_t)rows[r] * HH;
        gemm8<HH>(Arow, W_c1, c0, acc);
        const float* Brow[8];
#pragma unroll
        for (int r = 0; r < 8; ++r) Brow[r] = sHX + (rb + r) * HH;
        gemm8<HH>(Brow, W_c2, c0, acc);
        float4 b1 = *(const float4*)(b_c1 + c0);
        float4 b2 = *(const float4*)(b_c2 + c0);
#pragma unroll
        for (int r = 0; r < 8; ++r) {
            float4 ha = *(const float4*)(bufH + (size_t)rows[r] * HH + c0);
            float4 hx = *(const float4*)(sHX + (rb + r) * HH + c0);
            float4 v;
            v.x = fmaxf(ha.x + acc[r].x + b1.x + hx.x + b2.x, 0.f);
            v.y = fmaxf(ha.y + acc[r].y + b1.y + hx.y + b2.y, 0.f);
            v.z = fmaxf(ha.z + acc[r].z + b1.z + hx.z + b2.z, 0.f);
            v.w = fmaxf(ha.w + acc[r].w + b1.w + hx.w + b2.w, 0.f);
            *(float4*)(sOut + (rb + r) * HH + c0) = v;
        }
    }
    __syncthreads();

    // ---- phase C: h = relu(out @ W_f1 + b_f1) -> bufH (in place), + BN stats
    {
        float4 acc[8];
#pragma unroll
        for (int r = 0; r < 8; ++r) { acc[r].x = acc[r].y = acc[r].z = acc[r].w = 0.f; }
        const float* Arow[8];
#pragma unroll
        for (int r = 0; r < 8; ++r) Arow[r] = sOut + (rb + r) * HH;
        gemm8<HH>(Arow, W_f1, c0, acc);
        float4 b = *(const float4*)(b_f1 + c0);
        float4 s, q;
        s.x = s.y = s.z = s.w = 0.f;
        q.x = q.y = q.z = q.w = 0.f;
#pragma unroll
        for (int r = 0; r < 8; ++r) {
            float4 h;
            h.x = fmaxf(acc[r].x + b.x, 0.f);
            h.y = fmaxf(acc[r].y + b.y, 0.f);
            h.z = fmaxf(acc[r].z + b.z, 0.f);
            h.w = fmaxf(acc[r].w + b.w, 0.f);
            int gr = row0 + rb + r;
            if (gr < NN) {
                *(float4*)(bufH + (size_t)gr * HH + c0) = h;
                s.x += h.x; s.y += h.y; s.z += h.z; s.w += h.w;
                q.x += h.x * h.x; q.y += h.y * h.y; q.z += h.z * h.z; q.w += h.w * h.w;
            }
        }
        // block-level reduction in sHX scratch (sHX dead after phase B)
        float* red = sHX;
        red[(tr * HH + c0 + 0) * 2 + 0] = s.x; red[(tr * HH + c0 + 0) * 2 + 1] = q.x;
        red[(tr * HH + c0 + 1) * 2 + 0] = s.y; red[(tr * HH + c0 + 1) * 2 + 1] = q.y;
        red[(tr * HH + c0 + 2) * 2 + 0] = s.z; red[(tr * HH + c0 + 2) * 2 + 1] = q.z;
        red[(tr * HH + c0 + 3) * 2 + 0] = s.w; red[(tr * HH + c0 + 3) * 2 + 1] = q.w;
    }
    __syncthreads();
    if (tid < HH) {
        float s = 0.f, q = 0.f;
#pragma unroll
        for (int t = 0; t < 4; ++t) {
            s += sHX[(t * HH + tid) * 2 + 0];
            q += sHX[(t * HH + tid) * 2 + 1];
        }
        atomicAdd(&stats[tid], s);
        atomicAdd(&stats[HH + tid], q);
    }
}

// ---------------- BN fold: WT[j][c] = scale_c * W_f2[c][j]; bfold ----------------
__global__ void k_bnprep(const float* __restrict__ stats, const float* __restrict__ gamma,
                         const float* __restrict__ beta, const float* __restrict__ W_f2,
                         const float* __restrict__ b_f2, float* __restrict__ WT,
                         float* __restrict__ bfold) {
    __shared__ float sh[HH];
    const int c = threadIdx.x;
    const float invN = 1.0f / (float)NN;
    float mu = stats[c] * invN;
    float var = stats[HH + c] * invN - mu * mu;
    float scale = gamma[c] * rsqrtf(var + BN_EPS);
    float shift = beta[c] - mu * scale;
    sh[c] = shift;
    for (int j = 0; j < CC; ++j)
        WT[j * HH + c] = scale * W_f2[c * CC + j];
    __syncthreads();
    if (c < CC) {
        float b = b_f2[c];
        for (int k = 0; k < HH; ++k) b += sh[k] * W_f2[k * CC + c];
        bfold[c] = b;
    }
}

// ---------------- final: out = h @ WT^T + bfold ----------------
__global__ __launch_bounds__(320)
void k_final(const float* __restrict__ bufH, const float* __restrict__ WT,
             const float* __restrict__ bfold, float* __restrict__ out) {
    __shared__ float sH[32 * 260];  // padded stride 260 (bank-conflict-free)
    const int tid = threadIdx.x;
    const int row0 = blockIdx.x * 32;
    for (int i = tid; i < 32 * 64; i += 320) {
        int r = i >> 6, k4 = i & 63;
        int gr = row0 + r;
        if (gr >= NN) gr = NN - 1;
        float4 v = *(const float4*)(bufH + (size_t)gr * HH + k4 * 4);
        *(float4*)(sH + r * 260 + k4 * 4) = v;
    }
    __syncthreads();
    const int c = tid / 8, rl = tid % 8;
    const float bb = bfold[c];
    const float* wt = WT + (size_t)c * HH;
#pragma unroll
    for (int rr = 0; rr < 4; ++rr) {
        int r = rr * 8 + rl;
        int gr = row0 + r;
        float acc = bb;
        const float* hr = sH + r * 260;
#pragma unroll 8
        for (int k = 0; k < HH; k += 4) {
            float4 a = *(const float4*)(hr + k);
            float4 w = *(const float4*)(wt + k);
            acc += a.x * w.x + a.y * w.y + a.z * w.z + a.w * w.w;
        }
        if (gr < NN) out[(size_t)gr * CC + c] = acc;
    }
}

extern "C" void kernel_launch(void* const* d_in, const int* in_sizes, int n_in,
                              void* d_out, int out_size, void* d_ws, size_t ws_size,
                              hipStream_t stream) {
    const float* x      = (const float*)d_in[0];
    const int*   ei     = (const int*)d_in[1];
    const float* ew     = (const float*)d_in[2];
    const float* W_edge = (const float*)d_in[3];
    const float* b_edge = (const float*)d_in[4];
    const float* W_node = (const float*)d_in[5];
    const float* b_node = (const float*)d_in[6];
    const float* W_c1   = (const float*)d_in[7];
    const float* b_c1   = (const float*)d_in[8];
    const float* W_c2   = (const float*)d_in[9];
    const float* b_c2   = (const float*)d_in[10];
    const float* W_f1   = (const float*)d_in[11];
    const float* b_f1   = (const float*)d_in[12];
    const float* gamma  = (const float*)d_in[13];
    const float* beta   = (const float*)d_in[14];
    const float* W_f2   = (const float*)d_in[15];
    const float* b_f2   = (const float*)d_in[16];
    float* out = (float*)d_out;

    float* bufH  = (float*)d_ws;                  // N*H
    float* stats = bufH + (size_t)NN * HH;        // 2*H
    float* WT    = stats + 2 * HH;                // C*H
    float* bfold = WT + CC * HH;                  // C

    k_init<<<4096, 256, 0, stream>>>(bufH, stats, b_edge);
    k_scatter<<<EE / EPB, 256, 0, stream>>>(ei, ew, W_edge, bufH);
    k_fused<<<(NN + TM - 1) / TM, 256, 0, stream>>>(bufH, x, W_node, b_node, W_c1, b_c1,
                                                    W_c2, b_c2, W_f1, b_f1, stats);
    k_bnprep<<<1, 256, 0, stream>>>(stats, gamma, beta, W_f2, b_f2, WT, bfold);
    k_final<<<(NN + 31) / 32, 320, 0, stream>>>(bufH, WT, bfold, out);
}

// Round 2
// 840.927 us; speedup vs baseline: 1.4253x; 1.4253x over previous
//
#include <hip/hip_runtime.h>

#define NN 50000
#define EE 800000
#define FF 128
#define HH 256
#define CC 40
#define BN_EPS 1e-5f
#define TM 32

// ---------------- init: zero stats + degree counters ----------------
__global__ void k_init(float* __restrict__ stats, int* __restrict__ deg) {
    int i = blockIdx.x * blockDim.x + threadIdx.x;
    if (i < 2 * HH) stats[i] = 0.f;
    if (i < NN) deg[i] = 0;
}

// ---------------- histogram of dst ----------------
__global__ void k_hist(const int* __restrict__ ei, int* __restrict__ deg) {
    int e = blockIdx.x * blockDim.x + threadIdx.x;
    if (e < EE) atomicAdd(&deg[ei[EE + e]], 1);
}

// ---------------- single-block exclusive scan -> rowptr, pos ----------------
__global__ __launch_bounds__(1024)
void k_scan(const int* __restrict__ deg, int* __restrict__ rowptr, int* __restrict__ pos) {
    __shared__ int tile[1024];
    __shared__ int carry;
    if (threadIdx.x == 0) carry = 0;
    __syncthreads();
    for (int base = 0; base < NN; base += 1024) {
        int i = base + threadIdx.x;
        int v = (i < NN) ? deg[i] : 0;
        tile[threadIdx.x] = v;
        __syncthreads();
#pragma unroll
        for (int off = 1; off < 1024; off <<= 1) {
            int t = (threadIdx.x >= off) ? tile[threadIdx.x - off] : 0;
            __syncthreads();
            tile[threadIdx.x] += t;
            __syncthreads();
        }
        int incl = tile[threadIdx.x];
        int excl = incl - v;
        int base_out = carry;  // read before carry update
        if (i < NN) { rowptr[i] = base_out + excl; pos[i] = base_out + excl; }
        __syncthreads();
        if (threadIdx.x == 1023) carry += incl;
        __syncthreads();
    }
    if (threadIdx.x == 0) rowptr[NN] = carry;
}

// ---------------- bin-scatter (src, w) into CSR order ----------------
__global__ void k_ssort(const int* __restrict__ ei, const float* __restrict__ ew,
                        int* __restrict__ pos, int* __restrict__ ssrc,
                        float* __restrict__ sw) {
    int e = blockIdx.x * blockDim.x + threadIdx.x;
    if (e < EE) {
        int d = ei[EE + e];
        int p = atomicAdd(&pos[d], 1);
        ssrc[p] = ei[e];
        sw[p]   = ew[e];
    }
}

// ---------------- gather-accumulate: one wave per node ----------------
__global__ __launch_bounds__(256)
void k_gather(const int* __restrict__ rowptr, const int* __restrict__ ssrc,
              const float* __restrict__ sw, const float* __restrict__ W_edge,
              const float* __restrict__ b_edge, float* __restrict__ bufH) {
    const int wave = threadIdx.x >> 6;
    const int lane = threadIdx.x & 63;
    const int node = blockIdx.x * 4 + wave;
    if (node >= NN) return;
    const int beg = rowptr[node], end = rowptr[node + 1];
    const int c0 = lane * 4;
    float4 acc;
    acc.x = acc.y = acc.z = acc.w = 0.f;
    int e = beg;
    for (; e + 1 < end; e += 2) {
        int s0 = ssrc[e], s1 = ssrc[e + 1];
        float w0 = sw[e], w1 = sw[e + 1];
        float4 r0 = *(const float4*)(W_edge + (size_t)s0 * HH + c0);
        float4 r1 = *(const float4*)(W_edge + (size_t)s1 * HH + c0);
        acc.x += w0 * r0.x + w1 * r1.x;
        acc.y += w0 * r0.y + w1 * r1.y;
        acc.z += w0 * r0.z + w1 * r1.z;
        acc.w += w0 * r0.w + w1 * r1.w;
    }
    if (e < end) {
        int s0 = ssrc[e];
        float w0 = sw[e];
        float4 r0 = *(const float4*)(W_edge + (size_t)s0 * HH + c0);
        acc.x += w0 * r0.x;
        acc.y += w0 * r0.y;
        acc.z += w0 * r0.z;
        acc.w += w0 * r0.w;
    }
    float4 b = *(const float4*)(b_edge + c0);
    acc.x += b.x; acc.y += b.y; acc.z += b.z; acc.w += b.w;
    *(float4*)(bufH + (size_t)node * HH + c0) = acc;
}

// ---------------- 8-row x 4-col register-blocked GEMM helper ----------------
template <int K>
__device__ __forceinline__ void gemm8(const float* const* Arow, const float* __restrict__ W,
                                      int c0, float4 acc[8]) {
#pragma unroll 4
    for (int k = 0; k < K; k += 4) {
        float4 a[8];
#pragma unroll
        for (int r = 0; r < 8; ++r)
            a[r] = *(const float4*)(Arow[r] + k);
        float4 w0 = *(const float4*)(W + (size_t)(k + 0) * HH + c0);
        float4 w1 = *(const float4*)(W + (size_t)(k + 1) * HH + c0);
        float4 w2 = *(const float4*)(W + (size_t)(k + 2) * HH + c0);
        float4 w3 = *(const float4*)(W + (size_t)(k + 3) * HH + c0);
#pragma unroll
        for (int r = 0; r < 8; ++r) {
            acc[r].x += a[r].x * w0.x + a[r].y * w1.x + a[r].z * w2.x + a[r].w * w3.x;
            acc[r].y += a[r].x * w0.y + a[r].y * w1.y + a[r].z * w2.y + a[r].w * w3.y;
            acc[r].z += a[r].x * w0.z + a[r].y * w1.z + a[r].z * w2.z + a[r].w * w3.z;
            acc[r].w += a[r].x * w0.w + a[r].y * w1.w + a[r].z * w2.w + a[r].w * w3.w;
        }
    }
}

// ---------------- fused dense chain + BN stats ----------------
__global__ __launch_bounds__(256)
void k_fused(float* __restrict__ bufH, const float* __restrict__ x,
             const float* __restrict__ W_node, const float* __restrict__ b_node,
             const float* __restrict__ W_c1, const float* __restrict__ b_c1,
             const float* __restrict__ W_c2, const float* __restrict__ b_c2,
             const float* __restrict__ W_f1, const float* __restrict__ b_f1,
             float* __restrict__ stats) {
    __shared__ float sHX[TM * HH];   // 32 KB
    __shared__ float sOut[TM * HH];  // 32 KB
    const int tid = threadIdx.x;
    const int tc = tid & 63, tr = tid >> 6;
    const int c0 = tc * 4;
    const int rb = tr * 8;
    const int row0 = blockIdx.x * TM;

    int rows[8];
#pragma unroll
    for (int r = 0; r < 8; ++r) {
        int g = row0 + rb + r;
        rows[r] = g < NN ? g : NN - 1;
    }

    // ---- phase A: hx = x @ W_node + b_node -> sHX
    {
        float4 acc[8];
#pragma unroll
        for (int r = 0; r < 8; ++r) { acc[r].x = acc[r].y = acc[r].z = acc[r].w = 0.f; }
        const float* Arow[8];
#pragma unroll
        for (int r = 0; r < 8; ++r) Arow[r] = x + (size_t)rows[r] * FF;
        gemm8<FF>(Arow, W_node, c0, acc);
        float4 b = *(const float4*)(b_node + c0);
#pragma unroll
        for (int r = 0; r < 8; ++r) {
            float4 v;
            v.x = acc[r].x + b.x; v.y = acc[r].y + b.y;
            v.z = acc[r].z + b.z; v.w = acc[r].w + b.w;
            *(float4*)(sHX + (rb + r) * HH + c0) = v;
        }
    }
    __syncthreads();

    // ---- phase B: out = relu(ha + ha@Wc1 + bc1 + hx + hx@Wc2 + bc2) -> sOut
    {
        float4 acc[8];
#pragma unroll
        for (int r = 0; r < 8; ++r) { acc[r].x = acc[r].y = acc[r].z = acc[r].w = 0.f; }
        const float* Arow[8];
#pragma unroll
        for (int r = 0; r < 8; ++r) Arow[r] = bufH + (size_t)rows[r] * HH;
        gemm8<HH>(Arow, W_c1, c0, acc);
        const float* Brow[8];
#pragma unroll
        for (int r = 0; r < 8; ++r) Brow[r] = sHX + (rb + r) * HH;
        gemm8<HH>(Brow, W_c2, c0, acc);
        float4 b1 = *(const float4*)(b_c1 + c0);
        float4 b2 = *(const float4*)(b_c2 + c0);
#pragma unroll
        for (int r = 0; r < 8; ++r) {
            float4 ha = *(const float4*)(bufH + (size_t)rows[r] * HH + c0);
            float4 hx = *(const float4*)(sHX + (rb + r) * HH + c0);
            float4 v;
            v.x = fmaxf(ha.x + acc[r].x + b1.x + hx.x + b2.x, 0.f);
            v.y = fmaxf(ha.y + acc[r].y + b1.y + hx.y + b2.y, 0.f);
            v.z = fmaxf(ha.z + acc[r].z + b1.z + hx.z + b2.z, 0.f);
            v.w = fmaxf(ha.w + acc[r].w + b1.w + hx.w + b2.w, 0.f);
            *(float4*)(sOut + (rb + r) * HH + c0) = v;
        }
    }
    __syncthreads();

    // ---- phase C: h = relu(out @ W_f1 + b_f1) -> bufH (in place), + BN stats
    {
        float4 acc[8];
#pragma unroll
        for (int r = 0; r < 8; ++r) { acc[r].x = acc[r].y = acc[r].z = acc[r].w = 0.f; }
        const float* Arow[8];
#pragma unroll
        for (int r = 0; r < 8; ++r) Arow[r] = sOut + (rb + r) * HH;
        gemm8<HH>(Arow, W_f1, c0, acc);
        float4 b = *(const float4*)(b_f1 + c0);
        float4 s, q;
        s.x = s.y = s.z = s.w = 0.f;
        q.x = q.y = q.z = q.w = 0.f;
#pragma unroll
        for (int r = 0; r < 8; ++r) {
            float4 h;
            h.x = fmaxf(acc[r].x + b.x, 0.f);
            h.y = fmaxf(acc[r].y + b.y, 0.f);
            h.z = fmaxf(acc[r].z + b.z, 0.f);
            h.w = fmaxf(acc[r].w + b.w, 0.f);
            int gr = row0 + rb + r;
            if (gr < NN) {
                *(float4*)(bufH + (size_t)gr * HH + c0) = h;
                s.x += h.x; s.y += h.y; s.z += h.z; s.w += h.w;
                q.x += h.x * h.x; q.y += h.y * h.y; q.z += h.z * h.z; q.w += h.w * h.w;
            }
        }
        float* red = sHX;
        red[(tr * HH + c0 + 0) * 2 + 0] = s.x; red[(tr * HH + c0 + 0) * 2 + 1] = q.x;
        red[(tr * HH + c0 + 1) * 2 + 0] = s.y; red[(tr * HH + c0 + 1) * 2 + 1] = q.y;
        red[(tr * HH + c0 + 2) * 2 + 0] = s.z; red[(tr * HH + c0 + 2) * 2 + 1] = q.z;
        red[(tr * HH + c0 + 3) * 2 + 0] = s.w; red[(tr * HH + c0 + 3) * 2 + 1] = q.w;
    }
    __syncthreads();
    if (tid < HH) {
        float s = 0.f, q = 0.f;
#pragma unroll
        for (int t = 0; t < 4; ++t) {
            s += sHX[(t * HH + tid) * 2 + 0];
            q += sHX[(t * HH + tid) * 2 + 1];
        }
        atomicAdd(&stats[tid], s);
        atomicAdd(&stats[HH + tid], q);
    }
}

// ---------------- BN fold ----------------
__global__ void k_bnprep(const float* __restrict__ stats, const float* __restrict__ gamma,
                         const float* __restrict__ beta, const float* __restrict__ W_f2,
                         const float* __restrict__ b_f2, float* __restrict__ WT,
                         float* __restrict__ bfold) {
    __shared__ float sh[HH];
    const int c = threadIdx.x;
    const float invN = 1.0f / (float)NN;
    float mu = stats[c] * invN;
    float var = stats[HH + c] * invN - mu * mu;
    float scale = gamma[c] * rsqrtf(var + BN_EPS);
    float shift = beta[c] - mu * scale;
    sh[c] = shift;
    for (int j = 0; j < CC; ++j)
        WT[j * HH + c] = scale * W_f2[c * CC + j];
    __syncthreads();
    if (c < CC) {
        float b = b_f2[c];
        for (int k = 0; k < HH; ++k) b += sh[k] * W_f2[k * CC + c];
        bfold[c] = b;
    }
}

// ---------------- final: out = h @ WT^T + bfold ----------------
__global__ __launch_bounds__(320)
void k_final(const float* __restrict__ bufH, const float* __restrict__ WT,
             const float* __restrict__ bfold, float* __restrict__ out) {
    __shared__ float sH[32 * 260];
    const int tid = threadIdx.x;
    const int row0 = blockIdx.x * 32;
    for (int i = tid; i < 32 * 64; i += 320) {
        int r = i >> 6, k4 = i & 63;
        int gr = row0 + r;
        if (gr >= NN) gr = NN - 1;
        float4 v = *(const float4*)(bufH + (size_t)gr * HH + k4 * 4);
        *(float4*)(sH + r * 260 + k4 * 4) = v;
    }
    __syncthreads();
    const int c = tid / 8, rl = tid % 8;
    const float bb = bfold[c];
    const float* wt = WT + (size_t)c * HH;
#pragma unroll
    for (int rr = 0; rr < 4; ++rr) {
        int r = rr * 8 + rl;
        int gr = row0 + r;
        float acc = bb;
        const float* hr = sH + r * 260;
#pragma unroll 8
        for (int k = 0; k < HH; k += 4) {
            float4 a = *(const float4*)(hr + k);
            float4 w = *(const float4*)(wt + k);
            acc += a.x * w.x + a.y * w.y + a.z * w.z + a.w * w.w;
        }
        if (gr < NN) out[(size_t)gr * CC + c] = acc;
    }
}

extern "C" void kernel_launch(void* const* d_in, const int* in_sizes, int n_in,
                              void* d_out, int out_size, void* d_ws, size_t ws_size,
                              hipStream_t stream) {
    const float* x      = (const float*)d_in[0];
    const int*   ei     = (const int*)d_in[1];
    const float* ew     = (const float*)d_in[2];
    const float* W_edge = (const float*)d_in[3];
    const float* b_edge = (const float*)d_in[4];
    const float* W_node = (const float*)d_in[5];
    const float* b_node = (const float*)d_in[6];
    const float* W_c1   = (const float*)d_in[7];
    const float* b_c1   = (const float*)d_in[8];
    const float* W_c2   = (const float*)d_in[9];
    const float* b_c2   = (const float*)d_in[10];
    const float* W_f1   = (const float*)d_in[11];
    const float* b_f1   = (const float*)d_in[12];
    const float* gamma  = (const float*)d_in[13];
    const float* beta   = (const float*)d_in[14];
    const float* W_f2   = (const float*)d_in[15];
    const float* b_f2   = (const float*)d_in[16];
    float* out = (float*)d_out;

    float* bufH  = (float*)d_ws;                    // N*H floats
    float* stats = bufH + (size_t)NN * HH;          // 2*H
    float* WT    = stats + 2 * HH;                  // C*H
    float* bfold = WT + CC * HH;                    // C
    float* sw    = bfold + 64;                      // E floats
    int*   ibase = (int*)(sw + EE);
    int*   deg     = ibase;                         // N
    int*   rowptr  = deg + NN;                      // N+1
    int*   pos     = rowptr + NN + 1;               // N
    int*   ssrc    = pos + NN;                      // E

    k_init<<<(NN + 255) / 256, 256, 0, stream>>>(stats, deg);
    k_hist<<<(EE + 255) / 256, 256, 0, stream>>>(ei, deg);
    k_scan<<<1, 1024, 0, stream>>>(deg, rowptr, pos);
    k_ssort<<<(EE + 255) / 256, 256, 0, stream>>>(ei, ew, pos, ssrc, sw);
    k_gather<<<(NN + 3) / 4, 256, 0, stream>>>(rowptr, ssrc, sw, W_edge, b_edge, bufH);
    k_fused<<<(NN + TM - 1) / TM, 256, 0, stream>>>(bufH, x, W_node, b_node, W_c1, b_c1,
                                                    W_c2, b_c2, W_f1, b_f1, stats);
    k_bnprep<<<1, 256, 0, stream>>>(stats, gamma, beta, W_f2, b_f2, WT, bfold);
    k_final<<<(NN + 31) / 32, 320, 0, stream>>>(bufH, WT, bfold, out);
}

// Round 3
// 539.423 us; speedup vs baseline: 2.2220x; 1.5589x over previous
//
#include <hip/hip_runtime.h>

#define NN 50000
#define EE 800000
#define FF 128
#define HH 256
#define CC 40
#define BN_EPS 1e-5f

typedef float f4 __attribute__((ext_vector_type(4)));
typedef _Float16 h8 __attribute__((ext_vector_type(8)));
typedef _Float16 h4 __attribute__((ext_vector_type(4)));

// packed-weight half offsets: blocks of (kb,nb) -> 512 halves each
#define OFF_NODE 0            // 4*16 units
#define OFF_C1   32768        // 8*16 units
#define OFF_C2   98304
#define OFF_F1   163840
#define PW_HALVES 229376

#define SWZ(row, c2) ((c2) ^ (((row) & 7) << 4))

// ---------------- init: zero stats + degree ----------------
__global__ void k_init(float* __restrict__ stats, int* __restrict__ deg) {
    int i = blockIdx.x * blockDim.x + threadIdx.x;
    if (i < 2 * HH) stats[i] = 0.f;
    if (i < NN) deg[i] = 0;
}

// ---------------- pack weights into MFMA-B fragment layout (fp16) ----------------
__global__ __launch_bounds__(256)
void k_pack(const float* __restrict__ W_node, const float* __restrict__ W_c1,
            const float* __restrict__ W_c2, const float* __restrict__ W_f1,
            const float* __restrict__ b_node, const float* __restrict__ b_c1,
            const float* __restrict__ b_c2, _Float16* __restrict__ pW,
            float* __restrict__ bB) {
    const int tid = threadIdx.x;
    if (blockIdx.x == 112) {  // combined phase-B bias: b_c1+b_c2+b_node@(W_c2+I)
        int c = tid;
        if (c < HH) {
            float a = 0.f;
            for (int k = 0; k < HH; ++k) a += b_node[k] * W_c2[k * HH + c];
            bB[c] = a + b_node[c] + b_c1[c] + b_c2[c];
        }
        return;
    }
    const int unit = blockIdx.x * 4 + (tid >> 6);
    const int lane = tid & 63, lm = lane & 15, lg = lane >> 4;
    const float* Ws;
    bool addI;
    int u = unit;
    if (u < 64)       { Ws = W_node; addI = false; }
    else if (u < 192) { Ws = W_c1;   addI = true;  u -= 64; }
    else if (u < 320) { Ws = W_c2;   addI = true;  u -= 192; }
    else              { Ws = W_f1;   addI = false; u -= 320; }
    const int kb = u >> 4, nb = u & 15;
    h8 hv;
#pragma unroll
    for (int j = 0; j < 8; ++j) {
        int kr = kb * 32 + lg * 8 + j;
        int col = nb * 16 + lm;
        float v = Ws[kr * HH + col];
        if (addI && kr == col) v += 1.f;
        hv[j] = (_Float16)v;
    }
    *(h8*)(pW + (size_t)unit * 512 + lane * 8) = hv;
}

// ---------------- histogram of dst ----------------
__global__ void k_hist(const int* __restrict__ ei, int* __restrict__ deg) {
    int e = blockIdx.x * blockDim.x + threadIdx.x;
    if (e < EE) atomicAdd(&deg[ei[EE + e]], 1);
}

// ---------------- two-level scan ----------------
__global__ __launch_bounds__(256)
void k_scan1(const int* __restrict__ deg, int* __restrict__ rowptr, int* __restrict__ bsums) {
    __shared__ int t[256];
    const int tid = threadIdx.x;
    int i = blockIdx.x * 256 + tid;
    int v = (i < NN) ? deg[i] : 0;
    t[tid] = v;
    __syncthreads();
#pragma unroll
    for (int off = 1; off < 256; off <<= 1) {
        int u = (tid >= off) ? t[tid - off] : 0;
        __syncthreads();
        t[tid] += u;
        __syncthreads();
    }
    if (i < NN) rowptr[i] = t[tid] - v;
    if (tid == 255) bsums[blockIdx.x] = t[tid];
}
__global__ __launch_bounds__(256)
void k_scan2(int* __restrict__ bsums) {
    __shared__ int t[256];
    const int tid = threadIdx.x;
    int v = (tid < 196) ? bsums[tid] : 0;
    t[tid] = v;
    __syncthreads();
#pragma unroll
    for (int off = 1; off < 256; off <<= 1) {
        int u = (tid >= off) ? t[tid - off] : 0;
        __syncthreads();
        t[tid] += u;
        __syncthreads();
    }
    if (tid < 196) bsums[tid] = t[tid] - v;
}
__global__ __launch_bounds__(256)
void k_scan3(int* __restrict__ rowptr, const int* __restrict__ bsums, int* __restrict__ pos) {
    int i = blockIdx.x * 256 + threadIdx.x;
    if (i < NN) {
        int r = rowptr[i] + bsums[blockIdx.x];
        rowptr[i] = r;
        pos[i] = r;
    }
    if (i == 0) rowptr[NN] = EE;
}

// ---------------- bin-scatter (src, w) into CSR order ----------------
__global__ void k_ssort(const int* __restrict__ ei, const float* __restrict__ ew,
                        int* __restrict__ pos, int* __restrict__ ssrc,
                        float* __restrict__ sw) {
    int e = blockIdx.x * blockDim.x + threadIdx.x;
    if (e < EE) {
        int d = ei[EE + e];
        int p = atomicAdd(&pos[d], 1);
        ssrc[p] = ei[e];
        sw[p] = ew[e];
    }
}

// ---------------- gather-accumulate: one wave per node -> fp16 h_a ----------------
__global__ __launch_bounds__(256)
void k_gather(const int* __restrict__ rowptr, const int* __restrict__ ssrc,
              const float* __restrict__ sw, const float* __restrict__ W_edge,
              const float* __restrict__ b_edge, _Float16* __restrict__ bufHA) {
    const int wave = threadIdx.x >> 6;
    const int lane = threadIdx.x & 63;
    const int node = blockIdx.x * 4 + wave;
    if (node >= NN) return;
    const int beg = rowptr[node], end = rowptr[node + 1];
    const int c0 = lane * 4;
    f4 acc = {0.f, 0.f, 0.f, 0.f};
    int e = beg;
    for (; e + 1 < end; e += 2) {
        int s0 = ssrc[e], s1 = ssrc[e + 1];
        float w0 = sw[e], w1 = sw[e + 1];
        f4 r0 = *(const f4*)(W_edge + (size_t)s0 * HH + c0);
        f4 r1 = *(const f4*)(W_edge + (size_t)s1 * HH + c0);
        acc += w0 * r0 + w1 * r1;
    }
    if (e < end) {
        f4 r0 = *(const f4*)(W_edge + (size_t)ssrc[e] * HH + c0);
        acc += sw[e] * r0;
    }
    f4 b = *(const f4*)(b_edge + c0);
    acc += b;
    h4 hv;
    hv[0] = (_Float16)acc[0]; hv[1] = (_Float16)acc[1];
    hv[2] = (_Float16)acc[2]; hv[3] = (_Float16)acc[3];
    *(h4*)(bufHA + (size_t)node * HH + c0) = hv;
}

// ---------------- fused dense chain via fp16 MFMA ----------------
// block = 64 rows, 4 waves; wave w owns rows w*16..w*16+15.
// region1 sm[0..32K): sX (rs=256) then sA/sOUT (rs=512). region2 sm[32K..64K): sHX (rs=512), later sRed.
__global__ __launch_bounds__(256)
void k_fused(const _Float16* __restrict__ bufHA, const float* __restrict__ x,
             const _Float16* __restrict__ pW, const float* __restrict__ bB,
             const float* __restrict__ b_f1, _Float16* __restrict__ bufH,
             float* __restrict__ stats) {
    __shared__ __align__(16) char sm[65536];
    const int tid = threadIdx.x;
    const int wave = tid >> 6, l = tid & 63;
    const int lm = l & 15, lg = l >> 4;
    const int wr0 = wave * 16;
    const int row0 = blockIdx.x * 64;

    // ---- stage x tile fp32->fp16 -> region1 (rs=256), own rows
#pragma unroll
    for (int p = 0; p < 8; ++p) {
        int r = wr0 + p * 2 + (l >> 5);
        int gr = row0 + r;
        int c = l & 31;
        h4 hv = {(_Float16)0, (_Float16)0, (_Float16)0, (_Float16)0};
        if (gr < NN) {
            f4 v = *(const f4*)(x + (size_t)gr * FF + c * 4);
            hv[0] = (_Float16)v[0]; hv[1] = (_Float16)v[1];
            hv[2] = (_Float16)v[2]; hv[3] = (_Float16)v[3];
        }
        *(h4*)(sm + r * 256 + SWZ(r, c * 8)) = hv;
    }

    f4 acc[16];
    const f4 z4 = {0.f, 0.f, 0.f, 0.f};
#pragma unroll
    for (int nb = 0; nb < 16; ++nb) acc[nb] = z4;

    // ---- phase A: hx0 = x @ W_node (K=128), no bias (folded into bB)
    {
        const int ar = wr0 + lm;
#pragma unroll
        for (int kb = 0; kb < 4; ++kb) {
            h8 a = *(const h8*)(sm + ar * 256 + SWZ(ar, kb * 64 + lg * 16));
#pragma unroll
            for (int nb = 0; nb < 16; ++nb) {
                h8 b = *(const h8*)(pW + OFF_NODE + (size_t)(kb * 16 + nb) * 512 + l * 8);
                acc[nb] = __builtin_amdgcn_mfma_f32_16x16x32_f16(a, b, acc[nb], 0, 0, 0);
            }
        }
    }
    // epilogue A -> sHX (region2, rs=512) fp16, own rows
#pragma unroll
    for (int nb = 0; nb < 16; ++nb) {
#pragma unroll
        for (int q = 0; q < 4; ++q) {
            int r = wr0 + lg * 4 + q;
            int c2 = (nb * 16 + lm) * 2;
            *(_Float16*)(sm + 32768 + r * 512 + SWZ(r, c2)) = (_Float16)acc[nb][q];
        }
    }
    __syncthreads();  // barrier 1: all waves done with sX before region1 reuse

    // ---- stage h_a (fp16) -> region1 (rs=512), own rows
#pragma unroll
    for (int p = 0; p < 8; ++p) {
        int r = wr0 + p * 2 + (l >> 5);
        int gr = row0 + r;
        int c = l & 31;
        h8 hv = {(_Float16)0, (_Float16)0, (_Float16)0, (_Float16)0,
                 (_Float16)0, (_Float16)0, (_Float16)0, (_Float16)0};
        if (gr < NN) hv = *(const h8*)(bufHA + (size_t)gr * HH + c * 8);
        *(h8*)(sm + r * 512 + SWZ(r, c * 16)) = hv;
    }

#pragma unroll
    for (int nb = 0; nb < 16; ++nb) acc[nb] = z4;

    // ---- phase B: out = relu(h_a@(I+Wc1) + hx0@(I+Wc2) + bB)
    {
        const int ar = wr0 + lm;
#pragma unroll
        for (int kb = 0; kb < 8; ++kb) {
            h8 a = *(const h8*)(sm + ar * 512 + SWZ(ar, kb * 64 + lg * 16));
#pragma unroll
            for (int nb = 0; nb < 16; ++nb) {
                h8 b = *(const h8*)(pW + OFF_C1 + (size_t)(kb * 16 + nb) * 512 + l * 8);
                acc[nb] = __builtin_amdgcn_mfma_f32_16x16x32_f16(a, b, acc[nb], 0, 0, 0);
            }
        }
#pragma unroll
        for (int kb = 0; kb < 8; ++kb) {
            h8 a = *(const h8*)(sm + 32768 + ar * 512 + SWZ(ar, kb * 64 + lg * 16));
#pragma unroll
            for (int nb = 0; nb < 16; ++nb) {
                h8 b = *(const h8*)(pW + OFF_C2 + (size_t)(kb * 16 + nb) * 512 + l * 8);
                acc[nb] = __builtin_amdgcn_mfma_f32_16x16x32_f16(a, b, acc[nb], 0, 0, 0);
            }
        }
    }
    // epilogue B: +bias, relu -> region1 (own rows) fp16
#pragma unroll
    for (int nb = 0; nb < 16; ++nb) {
        float bb = bB[nb * 16 + lm];
#pragma unroll
        for (int q = 0; q < 4; ++q) {
            int r = wr0 + lg * 4 + q;
            float v = fmaxf(acc[nb][q] + bb, 0.f);
            int c2 = (nb * 16 + lm) * 2;
            *(_Float16*)(sm + r * 512 + SWZ(r, c2)) = (_Float16)v;
        }
    }
    __syncthreads();  // barrier 2: all waves done reading sHX (sRed aliases it)

#pragma unroll
    for (int nb = 0; nb < 16; ++nb) acc[nb] = z4;

    // ---- phase C: h = relu(out @ W_f1 + b_f1)
    {
        const int ar = wr0 + lm;
#pragma unroll
        for (int kb = 0; kb < 8; ++kb) {
            h8 a = *(const h8*)(sm + ar * 512 + SWZ(ar, kb * 64 + lg * 16));
#pragma unroll
            for (int nb = 0; nb < 16; ++nb) {
                h8 b = *(const h8*)(pW + OFF_F1 + (size_t)(kb * 16 + nb) * 512 + l * 8);
                acc[nb] = __builtin_amdgcn_mfma_f32_16x16x32_f16(a, b, acc[nb], 0, 0, 0);
            }
        }
    }
    // epilogue C: +bias, relu, store fp16, BN stats
    float* sRedS = (float*)(sm + 32768);          // [4][256]
    float* sRedQ = (float*)(sm + 32768 + 4096);   // [4][256]
#pragma unroll
    for (int nb = 0; nb < 16; ++nb) {
        float bb = b_f1[nb * 16 + lm];
        float s = 0.f, q = 0.f;
#pragma unroll
        for (int qq = 0; qq < 4; ++qq) {
            int r = wr0 + lg * 4 + qq;
            int gr = row0 + r;
            float v = fmaxf(acc[nb][qq] + bb, 0.f);
            if (gr < NN) {
                bufH[(size_t)gr * HH + nb * 16 + lm] = (_Float16)v;
                s += v;
                q += v * v;
            }
        }
        s += __shfl_xor(s, 16); s += __shfl_xor(s, 32);
        q += __shfl_xor(q, 16); q += __shfl_xor(q, 32);
        if (lg == 0) {
            sRedS[wave * 256 + nb * 16 + lm] = s;
            sRedQ[wave * 256 + nb * 16 + lm] = q;
        }
    }
    __syncthreads();  // barrier 3
    if (tid < HH) {
        float s = 0.f, q = 0.f;
#pragma unroll
        for (int w = 0; w < 4; ++w) {
            s += sRedS[w * 256 + tid];
            q += sRedQ[w * 256 + tid];
        }
        atomicAdd(&stats[tid], s);
        atomicAdd(&stats[HH + tid], q);
    }
}

// ---------------- BN fold ----------------
__global__ void k_bnprep(const float* __restrict__ stats, const float* __restrict__ gamma,
                         const float* __restrict__ beta, const float* __restrict__ W_f2,
                         const float* __restrict__ b_f2, float* __restrict__ WT,
                         float* __restrict__ bfold) {
    __shared__ float sh[HH];
    const int c = threadIdx.x;
    const float invN = 1.0f / (float)NN;
    float mu = stats[c] * invN;
    float var = stats[HH + c] * invN - mu * mu;
    float scale = gamma[c] * rsqrtf(var + BN_EPS);
    float shift = beta[c] - mu * scale;
    sh[c] = shift;
    for (int j = 0; j < CC; ++j)
        WT[j * HH + c] = scale * W_f2[c * CC + j];
    __syncthreads();
    if (c < CC) {
        float b = b_f2[c];
        for (int k = 0; k < HH; ++k) b += sh[k] * W_f2[k * CC + c];
        bfold[c] = b;
    }
}

// ---------------- final: out = h @ WT^T + bfold (h is fp16) ----------------
__global__ __launch_bounds__(320)
void k_final(const _Float16* __restrict__ bufH, const float* __restrict__ WT,
             const float* __restrict__ bfold, float* __restrict__ out) {
    __shared__ float sH[32 * 260];
    const int tid = threadIdx.x;
    const int row0 = blockIdx.x * 32;
    for (int i = tid; i < 32 * 32; i += 320) {
        int r = i >> 5, c8 = i & 31;
        int gr = row0 + r;
        if (gr >= NN) gr = NN - 1;
        h8 v = *(const h8*)(bufH + (size_t)gr * HH + c8 * 8);
        float* dst = sH + r * 260 + c8 * 8;
#pragma unroll
        for (int jj = 0; jj < 8; ++jj) dst[jj] = (float)v[jj];
    }
    __syncthreads();
    const int c = tid / 8, rl = tid % 8;
    const float bb = bfold[c];
    const float* wt = WT + (size_t)c * HH;
#pragma unroll
    for (int rr = 0; rr < 4; ++rr) {
        int r = rr * 8 + rl;
        int gr = row0 + r;
        float acc = bb;
        const float* hr = sH + r * 260;
#pragma unroll 8
        for (int k = 0; k < HH; k += 4) {
            f4 a = *(const f4*)(hr + k);
            f4 w = *(const f4*)(wt + k);
            acc += a[0] * w[0] + a[1] * w[1] + a[2] * w[2] + a[3] * w[3];
        }
        if (gr < NN) out[(size_t)gr * CC + c] = acc;
    }
}

extern "C" void kernel_launch(void* const* d_in, const int* in_sizes, int n_in,
                              void* d_out, int out_size, void* d_ws, size_t ws_size,
                              hipStream_t stream) {
    const float* x      = (const float*)d_in[0];
    const int*   ei     = (const int*)d_in[1];
    const float* ew     = (const float*)d_in[2];
    const float* W_edge = (const float*)d_in[3];
    const float* b_edge = (const float*)d_in[4];
    const float* W_node = (const float*)d_in[5];
    const float* b_node = (const float*)d_in[6];
    const float* W_c1   = (const float*)d_in[7];
    const float* b_c1   = (const float*)d_in[8];
    const float* W_c2   = (const float*)d_in[9];
    const float* b_c2   = (const float*)d_in[10];
    const float* W_f1   = (const float*)d_in[11];
    const float* b_f1   = (const float*)d_in[12];
    const float* gamma  = (const float*)d_in[13];
    const float* beta   = (const float*)d_in[14];
    const float* W_f2   = (const float*)d_in[15];
    const float* b_f2   = (const float*)d_in[16];
    float* out = (float*)d_out;

    _Float16* bufHA = (_Float16*)d_ws;                    // N*H fp16
    _Float16* bufH  = bufHA + (size_t)NN * HH;            // N*H fp16
    float* stats = (float*)(bufH + (size_t)NN * HH);      // 512
    float* bB    = stats + 2 * HH;                        // 256
    float* WT    = bB + HH;                               // C*H
    float* bfold = WT + CC * HH;                          // 64 (pad)
    float* sw    = bfold + 64;                            // E
    int* deg     = (int*)(sw + EE);                       // N
    int* rowptr  = deg + NN;                              // N+1
    int* pos     = rowptr + NN + 1;                       // N
    int* ssrc    = pos + NN;                              // E
    _Float16* pW = (_Float16*)(ssrc + EE);                // 229376 halves
    int* bsums   = (int*)(pW + PW_HALVES);                // 256

    k_init<<<196, 256, 0, stream>>>(stats, deg);
    k_pack<<<113, 256, 0, stream>>>(W_node, W_c1, W_c2, W_f1, b_node, b_c1, b_c2, pW, bB);
    k_hist<<<(EE + 255) / 256, 256, 0, stream>>>(ei, deg);
    k_scan1<<<196, 256, 0, stream>>>(deg, rowptr, bsums);
    k_scan2<<<1, 256, 0, stream>>>(bsums);
    k_scan3<<<196, 256, 0, stream>>>(rowptr, bsums, pos);
    k_ssort<<<(EE + 255) / 256, 256, 0, stream>>>(ei, ew, pos, ssrc, sw);
    k_gather<<<12500, 256, 0, stream>>>(rowptr, ssrc, sw, W_edge, b_edge, bufHA);
    k_fused<<<(NN + 63) / 64, 256, 0, stream>>>(bufHA, x, pW, bB, b_f1, bufH, stats);
    k_bnprep<<<1, 256, 0, stream>>>(stats, gamma, beta, W_f2, b_f2, WT, bfold);
    k_final<<<(NN + 31) / 32, 320, 0, stream>>>(bufH, WT, bfold, out);
}

// Round 4
// 428.294 us; speedup vs baseline: 2.7985x; 1.2595x over previous
//
#include <hip/hip_runtime.h>

#define NN 50000
#define EE 800000
#define FF 128
#define HH 256
#define CC 40
#define BN_EPS 1e-5f

typedef float f4 __attribute__((ext_vector_type(4)));
typedef _Float16 h8 __attribute__((ext_vector_type(8)));
typedef _Float16 h4 __attribute__((ext_vector_type(4)));

// packed-weight half offsets: blocks of (kb,nb) -> 512 halves each
#define OFF_NODE 0            // 4*16 units
#define OFF_C1   32768        // 8*16 units
#define OFF_C2   98304
#define OFF_F1   163840
#define PW_HALVES 229376

#define SWZ(row, c2) ((c2) ^ (((row) & 7) << 4))

// ---------------- init: zero stats + degree ----------------
__global__ void k_init(float* __restrict__ stats, int* __restrict__ deg) {
    int i = blockIdx.x * blockDim.x + threadIdx.x;
    if (i < 2 * HH) stats[i] = 0.f;
    if (i < NN) deg[i] = 0;
}

// ---------------- x -> fp16 ----------------
__global__ void k_cvt(const float* __restrict__ x, _Float16* __restrict__ x16) {
    int i = blockIdx.x * blockDim.x + threadIdx.x;
    if (i < NN * FF / 4) {
        f4 v = ((const f4*)x)[i];
        h4 h;
        h[0] = (_Float16)v[0]; h[1] = (_Float16)v[1];
        h[2] = (_Float16)v[2]; h[3] = (_Float16)v[3];
        ((h4*)x16)[i] = h;
    }
}

// ---------------- pack weights into MFMA-B fragment layout (fp16) ----------------
__global__ __launch_bounds__(256)
void k_pack(const float* __restrict__ W_node, const float* __restrict__ W_c1,
            const float* __restrict__ W_c2, const float* __restrict__ W_f1,
            const float* __restrict__ b_node, const float* __restrict__ b_c1,
            const float* __restrict__ b_c2, _Float16* __restrict__ pW,
            float* __restrict__ bB) {
    const int tid = threadIdx.x;
    if (blockIdx.x == 112) {  // combined phase-B bias: b_c1+b_c2+b_node@(I+W_c2)
        int c = tid;
        if (c < HH) {
            float a = 0.f;
            for (int k = 0; k < HH; ++k) a += b_node[k] * W_c2[k * HH + c];
            bB[c] = a + b_node[c] + b_c1[c] + b_c2[c];
        }
        return;
    }
    const int unit = blockIdx.x * 4 + (tid >> 6);
    const int lane = tid & 63, lm = lane & 15, lg = lane >> 4;
    const float* Ws;
    bool addI;
    int u = unit;
    if (u < 64)       { Ws = W_node; addI = false; }
    else if (u < 192) { Ws = W_c1;   addI = true;  u -= 64; }
    else if (u < 320) { Ws = W_c2;   addI = true;  u -= 192; }
    else              { Ws = W_f1;   addI = false; u -= 320; }
    const int kb = u >> 4, nb = u & 15;
    h8 hv;
#pragma unroll
    for (int j = 0; j < 8; ++j) {
        int kr = kb * 32 + lg * 8 + j;
        int col = nb * 16 + lm;
        float v = Ws[kr * HH + col];
        if (addI && kr == col) v += 1.f;
        hv[j] = (_Float16)v;
    }
    *(h8*)(pW + (size_t)unit * 512 + lane * 8) = hv;
}

// ---------------- histogram of dst ----------------
__global__ void k_hist(const int* __restrict__ ei, int* __restrict__ deg) {
    int e = blockIdx.x * blockDim.x + threadIdx.x;
    if (e < EE) atomicAdd(&deg[ei[EE + e]], 1);
}

// ---------------- two-level scan ----------------
__global__ __launch_bounds__(256)
void k_scan1(const int* __restrict__ deg, int* __restrict__ rowptr, int* __restrict__ bsums) {
    __shared__ int t[256];
    const int tid = threadIdx.x;
    int i = blockIdx.x * 256 + tid;
    int v = (i < NN) ? deg[i] : 0;
    t[tid] = v;
    __syncthreads();
#pragma unroll
    for (int off = 1; off < 256; off <<= 1) {
        int u = (tid >= off) ? t[tid - off] : 0;
        __syncthreads();
        t[tid] += u;
        __syncthreads();
    }
    if (i < NN) rowptr[i] = t[tid] - v;
    if (tid == 255) bsums[blockIdx.x] = t[tid];
}
__global__ __launch_bounds__(256)
void k_scan2(int* __restrict__ bsums) {
    __shared__ int t[256];
    const int tid = threadIdx.x;
    int v = (tid < 196) ? bsums[tid] : 0;
    t[tid] = v;
    __syncthreads();
#pragma unroll
    for (int off = 1; off < 256; off <<= 1) {
        int u = (tid >= off) ? t[tid - off] : 0;
        __syncthreads();
        t[tid] += u;
        __syncthreads();
    }
    if (tid < 196) bsums[tid] = t[tid] - v;
}
__global__ __launch_bounds__(256)
void k_scan3(int* __restrict__ rowptr, const int* __restrict__ bsums, int* __restrict__ pos) {
    int i = blockIdx.x * 256 + threadIdx.x;
    if (i < NN) {
        int r = rowptr[i] + bsums[blockIdx.x];
        rowptr[i] = r;
        pos[i] = r;
    }
    if (i == 0) rowptr[NN] = EE;
}

// ---------------- bin-scatter (src, w) into CSR order ----------------
__global__ void k_ssort(const int* __restrict__ ei, const float* __restrict__ ew,
                        int* __restrict__ pos, int* __restrict__ ssrc,
                        float* __restrict__ sw) {
    int e = blockIdx.x * blockDim.x + threadIdx.x;
    if (e < EE) {
        int d = ei[EE + e];
        int p = atomicAdd(&pos[d], 1);
        ssrc[p] = ei[e];
        sw[p] = ew[e];
    }
}

// ---------------- gather-accumulate: one wave per node -> fp16 h_a ----------------
__global__ __launch_bounds__(256)
void k_gather(const int* __restrict__ rowptr, const int* __restrict__ ssrc,
              const float* __restrict__ sw, const float* __restrict__ W_edge,
              const float* __restrict__ b_edge, _Float16* __restrict__ bufHA) {
    const int wave = threadIdx.x >> 6;
    const int lane = threadIdx.x & 63;
    const int node = blockIdx.x * 4 + wave;
    if (node >= NN) return;
    const int beg = rowptr[node], end = rowptr[node + 1];
    const int c0 = lane * 4;
    f4 acc = {0.f, 0.f, 0.f, 0.f};
    int e = beg;
    for (; e + 1 < end; e += 2) {
        int s0 = ssrc[e], s1 = ssrc[e + 1];
        float w0 = sw[e], w1 = sw[e + 1];
        f4 r0 = *(const f4*)(W_edge + (size_t)s0 * HH + c0);
        f4 r1 = *(const f4*)(W_edge + (size_t)s1 * HH + c0);
        acc += w0 * r0 + w1 * r1;
    }
    if (e < end) {
        f4 r0 = *(const f4*)(W_edge + (size_t)ssrc[e] * HH + c0);
        acc += sw[e] * r0;
    }
    f4 b = *(const f4*)(b_edge + c0);
    acc += b;
    h4 hv;
    hv[0] = (_Float16)acc[0]; hv[1] = (_Float16)acc[1];
    hv[2] = (_Float16)acc[2]; hv[3] = (_Float16)acc[3];
    *(h4*)(bufHA + (size_t)node * HH + c0) = hv;
}

// ---------------- weight-stationary streaming GEMM ----------------
// block = 256 thr (4 waves). Wave w owns output cols [w*64, w*64+64).
// Weights in registers (KB x 4 fragments). A-tiles (32 rows x K) streamed
// through swizzled LDS with register prefetch. MODE: 0/1 = plain store,
// 2 = relu(acc + T + bias), 3 = relu(acc + bias) + BN stats.
template <int KB, int MODE>
__global__ __launch_bounds__(256, 2)
void k_gemm(const _Float16* __restrict__ A, const _Float16* __restrict__ pWph,
            const _Float16* __restrict__ T, const float* __restrict__ bias,
            _Float16* __restrict__ C, float* __restrict__ stats) {
    constexpr int K = KB * 32;        // 128 or 256
    constexpr int RB = K * 2;         // row bytes in LDS
    constexpr int KW = KB * 4;        // 16B units per row
    constexpr int U = (32 * KW) / 256;  // 16B units per thread per tile
    __shared__ __align__(16) char sA[32 * RB];
    const int tid = threadIdx.x;
    const int w = tid >> 6, l = tid & 63;
    const int lm = l & 15, lg = l >> 4;

    // ---- load weight fragments (once)
    h8 wreg[KB][4];
#pragma unroll
    for (int kb = 0; kb < KB; ++kb)
#pragma unroll
        for (int n = 0; n < 4; ++n)
            wreg[kb][n] = *(const h8*)(pWph + (size_t)(kb * 16 + w * 4 + n) * 512 + l * 8);

    float breg[4];
    if constexpr (MODE >= 2) {
#pragma unroll
        for (int n = 0; n < 4; ++n) breg[n] = bias[w * 64 + n * 16 + lm];
    }
    float sS[4] = {0.f, 0.f, 0.f, 0.f}, sQ[4] = {0.f, 0.f, 0.f, 0.f};

    const int NT = (NN + 31) / 32;
    int4 pre[U];
    int t = blockIdx.x;
    {
#pragma unroll
        for (int j = 0; j < U; ++j) {
            int unit = tid * U + j;
            int r = unit / KW, s = unit % KW;
            int grow = t * 32 + r;
            int4 z = {0, 0, 0, 0};
            pre[j] = (grow < NN) ? *(const int4*)(A + (size_t)grow * K + s * 8) : z;
        }
    }

    for (; t < NT; t += gridDim.x) {
        __syncthreads();  // previous compute done with sA
#pragma unroll
        for (int j = 0; j < U; ++j) {
            int unit = tid * U + j;
            int r = unit / KW, s = unit % KW;
            *(int4*)(sA + r * RB + SWZ(r, s * 16)) = pre[j];
        }
        int tn = t + gridDim.x;
        if (tn < NT) {
#pragma unroll
            for (int j = 0; j < U; ++j) {
                int unit = tid * U + j;
                int r = unit / KW, s = unit % KW;
                int grow = tn * 32 + r;
                int4 z = {0, 0, 0, 0};
                pre[j] = (grow < NN) ? *(const int4*)(A + (size_t)grow * K + s * 8) : z;
            }
        }
        __syncthreads();  // staging visible

        f4 acc[2][4];
        const f4 z4 = {0.f, 0.f, 0.f, 0.f};
#pragma unroll
        for (int rf = 0; rf < 2; ++rf)
#pragma unroll
            for (int n = 0; n < 4; ++n) acc[rf][n] = z4;

#pragma unroll
        for (int kb = 0; kb < KB; ++kb) {
            h8 a0 = *(const h8*)(sA + lm * RB + SWZ(lm, kb * 64 + lg * 16));
            h8 a1 = *(const h8*)(sA + (16 + lm) * RB + SWZ(16 + lm, kb * 64 + lg * 16));
#pragma unroll
            for (int n = 0; n < 4; ++n) {
                acc[0][n] = __builtin_amdgcn_mfma_f32_16x16x32_f16(a0, wreg[kb][n], acc[0][n], 0, 0, 0);
                acc[1][n] = __builtin_amdgcn_mfma_f32_16x16x32_f16(a1, wreg[kb][n], acc[1][n], 0, 0, 0);
            }
        }

        // ---- epilogue
        const int row0 = t * 32;
#pragma unroll
        for (int rf = 0; rf < 2; ++rf)
#pragma unroll
            for (int n = 0; n < 4; ++n) {
                const int col = w * 64 + n * 16 + lm;
#pragma unroll
                for (int q = 0; q < 4; ++q) {
                    int grow = row0 + rf * 16 + lg * 4 + q;
                    if (grow < NN) {
                        float v = acc[rf][n][q];
                        if constexpr (MODE == 2)
                            v = fmaxf(v + (float)T[(size_t)grow * HH + col] + breg[n], 0.f);
                        if constexpr (MODE == 3) {
                            v = fmaxf(v + breg[n], 0.f);
                            sS[n] += v;
                            sQ[n] += v * v;
                        }
                        C[(size_t)grow * HH + col] = (_Float16)v;
                    }
                }
            }
    }

    if constexpr (MODE == 3) {
#pragma unroll
        for (int n = 0; n < 4; ++n) {
            float s = sS[n];
            s += __shfl_xor(s, 16); s += __shfl_xor(s, 32);
            float q = sQ[n];
            q += __shfl_xor(q, 16); q += __shfl_xor(q, 32);
            if (lg == 0) {
                atomicAdd(&stats[w * 64 + n * 16 + lm], s);
                atomicAdd(&stats[HH + w * 64 + n * 16 + lm], q);
            }
        }
    }
}

// ---------------- BN fold ----------------
__global__ void k_bnprep(const float* __restrict__ stats, const float* __restrict__ gamma,
                         const float* __restrict__ beta, const float* __restrict__ W_f2,
                         const float* __restrict__ b_f2, float* __restrict__ WT,
                         float* __restrict__ bfold) {
    __shared__ float sh[HH];
    const int c = threadIdx.x;
    const float invN = 1.0f / (float)NN;
    float mu = stats[c] * invN;
    float var = stats[HH + c] * invN - mu * mu;
    float scale = gamma[c] * rsqrtf(var + BN_EPS);
    float shift = beta[c] - mu * scale;
    sh[c] = shift;
    for (int j = 0; j < CC; ++j)
        WT[j * HH + c] = scale * W_f2[c * CC + j];
    __syncthreads();
    if (c < CC) {
        float b = b_f2[c];
        for (int k = 0; k < HH; ++k) b += sh[k] * W_f2[k * CC + c];
        bfold[c] = b;
    }
}

// ---------------- final: out = h @ WT^T + bfold (h is fp16) ----------------
__global__ __launch_bounds__(320)
void k_final(const _Float16* __restrict__ bufH, const float* __restrict__ WT,
             const float* __restrict__ bfold, float* __restrict__ out) {
    __shared__ float sH[32 * 260];
    const int tid = threadIdx.x;
    const int row0 = blockIdx.x * 32;
    for (int i = tid; i < 32 * 32; i += 320) {
        int r = i >> 5, c8 = i & 31;
        int gr = row0 + r;
        if (gr >= NN) gr = NN - 1;
        h8 v = *(const h8*)(bufH + (size_t)gr * HH + c8 * 8);
        float* dst = sH + r * 260 + c8 * 8;
#pragma unroll
        for (int jj = 0; jj < 8; ++jj) dst[jj] = (float)v[jj];
    }
    __syncthreads();
    const int c = tid / 8, rl = tid % 8;
    const float bb = bfold[c];
    const float* wt = WT + (size_t)c * HH;
#pragma unroll
    for (int rr = 0; rr < 4; ++rr) {
        int r = rr * 8 + rl;
        int gr = row0 + r;
        float acc = bb;
        const float* hr = sH + r * 260;
#pragma unroll 8
        for (int k = 0; k < HH; k += 4) {
            f4 a = *(const f4*)(hr + k);
            f4 w = *(const f4*)(wt + k);
            acc += a[0] * w[0] + a[1] * w[1] + a[2] * w[2] + a[3] * w[3];
        }
        if (gr < NN) out[(size_t)gr * CC + c] = acc;
    }
}

extern "C" void kernel_launch(void* const* d_in, const int* in_sizes, int n_in,
                              void* d_out, int out_size, void* d_ws, size_t ws_size,
                              hipStream_t stream) {
    const float* x      = (const float*)d_in[0];
    const int*   ei     = (const int*)d_in[1];
    const float* ew     = (const float*)d_in[2];
    const float* W_edge = (const float*)d_in[3];
    const float* b_edge = (const float*)d_in[4];
    const float* W_node = (const float*)d_in[5];
    const float* b_node = (const float*)d_in[6];
    const float* W_c1   = (const float*)d_in[7];
    const float* b_c1   = (const float*)d_in[8];
    const float* W_c2   = (const float*)d_in[9];
    const float* b_c2   = (const float*)d_in[10];
    const float* W_f1   = (const float*)d_in[11];
    const float* b_f1   = (const float*)d_in[12];
    const float* gamma  = (const float*)d_in[13];
    const float* beta   = (const float*)d_in[14];
    const float* W_f2   = (const float*)d_in[15];
    const float* b_f2   = (const float*)d_in[16];
    float* out = (float*)d_out;

    // buf1: x16 (first half) -> tmp ; buf2: h_a -> outB ; buf3: hx0 -> h
    _Float16* buf1 = (_Float16*)d_ws;
    _Float16* buf2 = buf1 + (size_t)NN * HH;
    _Float16* buf3 = buf2 + (size_t)NN * HH;
    float* stats = (float*)(buf3 + (size_t)NN * HH);      // 512
    float* bB    = stats + 2 * HH;                        // 256
    float* WT    = bB + HH;                               // C*H
    float* bfold = WT + CC * HH;                          // 64 (pad)
    float* sw    = bfold + 64;                            // E
    int* deg     = (int*)(sw + EE);                       // N
    int* rowptr  = deg + NN;                              // N+1
    int* pos     = rowptr + NN + 1;                       // N
    int* ssrc    = pos + NN;                              // E
    _Float16* pW = (_Float16*)(ssrc + EE);                // 229376 halves
    int* bsums   = (int*)(pW + PW_HALVES);                // 256

    k_init<<<196, 256, 0, stream>>>(stats, deg);
    k_pack<<<113, 256, 0, stream>>>(W_node, W_c1, W_c2, W_f1, b_node, b_c1, b_c2, pW, bB);
    k_cvt<<<(NN * FF / 4 + 255) / 256, 256, 0, stream>>>(x, buf1);
    k_hist<<<(EE + 255) / 256, 256, 0, stream>>>(ei, deg);
    k_scan1<<<196, 256, 0, stream>>>(deg, rowptr, bsums);
    k_scan2<<<1, 256, 0, stream>>>(bsums);
    k_scan3<<<196, 256, 0, stream>>>(rowptr, bsums, pos);
    k_ssort<<<(EE + 255) / 256, 256, 0, stream>>>(ei, ew, pos, ssrc, sw);
    k_gather<<<12500, 256, 0, stream>>>(rowptr, ssrc, sw, W_edge, b_edge, buf2);

    // GA: hx0 = x16 @ W_node                  (K=128) -> buf3
    k_gemm<4, 0><<<512, 256, 0, stream>>>(buf1, pW + OFF_NODE, nullptr, nullptr, buf3, nullptr);
    // GB1: tmp = h_a @ (I+W_c1)               (K=256) -> buf1
    k_gemm<8, 1><<<512, 256, 0, stream>>>(buf2, pW + OFF_C1, nullptr, nullptr, buf1, nullptr);
    // GB2: outB = relu(hx0 @ (I+W_c2) + tmp + bB)     -> buf2
    k_gemm<8, 2><<<512, 256, 0, stream>>>(buf3, pW + OFF_C2, buf1, bB, buf2, nullptr);
    // GC: h = relu(outB @ W_f1 + b_f1) + BN stats     -> buf3
    k_gemm<8, 3><<<512, 256, 0, stream>>>(buf2, pW + OFF_F1, nullptr, b_f1, buf3, stats);

    k_bnprep<<<1, 256, 0, stream>>>(stats, gamma, beta, W_f2, b_f2, WT, bfold);
    k_final<<<(NN + 31) / 32, 320, 0, stream>>>(buf3, WT, bfold, out);
}

// Round 5
// 338.995 us; speedup vs baseline: 3.5357x; 1.2634x over previous
//
#include <hip/hip_runtime.h>

#define NN 50000
#define EE 800000
#define FF 128
#define HH 256
#define CC 40
#define BN_EPS 1e-5f

typedef float f4 __attribute__((ext_vector_type(4)));
typedef _Float16 h8 __attribute__((ext_vector_type(8)));
typedef _Float16 h4 __attribute__((ext_vector_type(4)));

// packed-weight half offsets: blocks of (kb,nb) -> 512 halves each
#define OFF_NODE 0            // 4*16 units
#define OFF_C1   32768        // 8*16 units
#define OFF_C2   98304
#define OFF_F1   163840
#define PW_HALVES 229376

#define SWZ(row, c2) ((c2) ^ (((row) & 7) << 4))

// ---------------- init: zero stats + degree ----------------
__global__ void k_init(float* __restrict__ stats, int* __restrict__ deg) {
    int i = blockIdx.x * blockDim.x + threadIdx.x;
    if (i < 2 * HH) stats[i] = 0.f;
    if (i < NN) deg[i] = 0;
}

// ---------------- W_edge -> fp16 ----------------
__global__ void k_cvtW(const float* __restrict__ W, _Float16* __restrict__ W16) {
    int i = blockIdx.x * blockDim.x + threadIdx.x;
    if (i < NN * HH / 8) {
        f4 v0 = ((const f4*)W)[i * 2];
        f4 v1 = ((const f4*)W)[i * 2 + 1];
        h8 h;
        h[0] = (_Float16)v0[0]; h[1] = (_Float16)v0[1];
        h[2] = (_Float16)v0[2]; h[3] = (_Float16)v0[3];
        h[4] = (_Float16)v1[0]; h[5] = (_Float16)v1[1];
        h[6] = (_Float16)v1[2]; h[7] = (_Float16)v1[3];
        ((h8*)W16)[i] = h;
    }
}

// ---------------- pack weights into MFMA-B fragment layout (fp16) ----------------
__global__ __launch_bounds__(256)
void k_pack(const float* __restrict__ W_node, const float* __restrict__ W_c1,
            const float* __restrict__ W_c2, const float* __restrict__ W_f1,
            const float* __restrict__ b_node, const float* __restrict__ b_c1,
            const float* __restrict__ b_c2, _Float16* __restrict__ pW,
            float* __restrict__ bB) {
    const int tid = threadIdx.x;
    if (blockIdx.x == 112) {  // combined phase-B bias: b_c1+b_c2+b_node@(I+W_c2)
        int c = tid;
        if (c < HH) {
            float a = 0.f;
            for (int k = 0; k < HH; ++k) a += b_node[k] * W_c2[k * HH + c];
            bB[c] = a + b_node[c] + b_c1[c] + b_c2[c];
        }
        return;
    }
    const int unit = blockIdx.x * 4 + (tid >> 6);
    const int lane = tid & 63, lm = lane & 15, lg = lane >> 4;
    const float* Ws;
    bool addI;
    int u = unit;
    if (u < 64)       { Ws = W_node; addI = false; }
    else if (u < 192) { Ws = W_c1;   addI = true;  u -= 64; }
    else if (u < 320) { Ws = W_c2;   addI = true;  u -= 192; }
    else              { Ws = W_f1;   addI = false; u -= 320; }
    const int kb = u >> 4, nb = u & 15;
    h8 hv;
#pragma unroll
    for (int j = 0; j < 8; ++j) {
        int kr = kb * 32 + lg * 8 + j;
        int col = nb * 16 + lm;
        float v = Ws[kr * HH + col];
        if (addI && kr == col) v += 1.f;
        hv[j] = (_Float16)v;
    }
    *(h8*)(pW + (size_t)unit * 512 + lane * 8) = hv;
}

// ---------------- histogram of dst ----------------
__global__ void k_hist(const int* __restrict__ ei, int* __restrict__ deg) {
    int e = blockIdx.x * blockDim.x + threadIdx.x;
    if (e < EE) atomicAdd(&deg[ei[EE + e]], 1);
}

// ---------------- two-level scan ----------------
__global__ __launch_bounds__(256)
void k_scan1(const int* __restrict__ deg, int* __restrict__ rowptr, int* __restrict__ bsums) {
    __shared__ int t[256];
    const int tid = threadIdx.x;
    int i = blockIdx.x * 256 + tid;
    int v = (i < NN) ? deg[i] : 0;
    t[tid] = v;
    __syncthreads();
#pragma unroll
    for (int off = 1; off < 256; off <<= 1) {
        int u = (tid >= off) ? t[tid - off] : 0;
        __syncthreads();
        t[tid] += u;
        __syncthreads();
    }
    if (i < NN) rowptr[i] = t[tid] - v;
    if (tid == 255) bsums[blockIdx.x] = t[tid];
}
__global__ __launch_bounds__(256)
void k_scan2(int* __restrict__ bsums) {
    __shared__ int t[256];
    const int tid = threadIdx.x;
    int v = (tid < 196) ? bsums[tid] : 0;
    t[tid] = v;
    __syncthreads();
#pragma unroll
    for (int off = 1; off < 256; off <<= 1) {
        int u = (tid >= off) ? t[tid - off] : 0;
        __syncthreads();
        t[tid] += u;
        __syncthreads();
    }
    if (tid < 196) bsums[tid] = t[tid] - v;
}
__global__ __launch_bounds__(256)
void k_scan3(int* __restrict__ rowptr, const int* __restrict__ bsums, int* __restrict__ pos) {
    int i = blockIdx.x * 256 + threadIdx.x;
    if (i < NN) {
        int r = rowptr[i] + bsums[blockIdx.x];
        rowptr[i] = r;
        pos[i] = r;
    }
    if (i == 0) rowptr[NN] = EE;
}

// ---------------- bin-scatter (src, w) into CSR order ----------------
__global__ void k_ssort(const int* __restrict__ ei, const float* __restrict__ ew,
                        int* __restrict__ pos, int* __restrict__ ssrc,
                        float* __restrict__ sw) {
    int e = blockIdx.x * blockDim.x + threadIdx.x;
    if (e < EE) {
        int d = ei[EE + e];
        int p = atomicAdd(&pos[d], 1);
        ssrc[p] = ei[e];
        sw[p] = ew[e];
    }
}

// ---------------- gather-accumulate: one wave per node (fp16 W_edge) ----------------
__global__ __launch_bounds__(256)
void k_gather(const int* __restrict__ rowptr, const int* __restrict__ ssrc,
              const float* __restrict__ sw, const _Float16* __restrict__ W16,
              const float* __restrict__ b_edge, _Float16* __restrict__ bufHA) {
    const int wave = threadIdx.x >> 6;
    const int lane = threadIdx.x & 63;
    const int node = blockIdx.x * 4 + wave;
    if (node >= NN) return;
    const int beg = rowptr[node], end = rowptr[node + 1];
    const int c0 = lane * 4;
    f4 acc = {0.f, 0.f, 0.f, 0.f};
    int e = beg;
    for (; e + 1 < end; e += 2) {
        int s0 = ssrc[e], s1 = ssrc[e + 1];
        float w0 = sw[e], w1 = sw[e + 1];
        h4 r0 = *(const h4*)(W16 + (size_t)s0 * HH + c0);
        h4 r1 = *(const h4*)(W16 + (size_t)s1 * HH + c0);
        f4 f0 = {(float)r0[0], (float)r0[1], (float)r0[2], (float)r0[3]};
        f4 f1 = {(float)r1[0], (float)r1[1], (float)r1[2], (float)r1[3]};
        acc += w0 * f0 + w1 * f1;
    }
    if (e < end) {
        h4 r0 = *(const h4*)(W16 + (size_t)ssrc[e] * HH + c0);
        f4 f0 = {(float)r0[0], (float)r0[1], (float)r0[2], (float)r0[3]};
        acc += sw[e] * f0;
    }
    f4 b = *(const f4*)(b_edge + c0);
    acc += b;
    h4 hv;
    hv[0] = (_Float16)acc[0]; hv[1] = (_Float16)acc[1];
    hv[2] = (_Float16)acc[2]; hv[3] = (_Float16)acc[3];
    *(h4*)(bufHA + (size_t)node * HH + c0) = hv;
}

// ---------------- weight-stationary streaming GEMM (single matrix) ----------------
// block = 256 thr (4 waves). Wave w owns output cols [w*64, w*64+64).
// MODE: 0 = plain store, 1 = relu(acc+bias) + BN stats. SRC32: A is fp32.
template <int KB, int MODE, int SRC32>
__global__ __launch_bounds__(256, 2)
void k_gemm(const void* __restrict__ Av, const _Float16* __restrict__ pWph,
            const float* __restrict__ bias, _Float16* __restrict__ C,
            float* __restrict__ stats) {
    constexpr int K = KB * 32;
    constexpr int RB = K * 2;           // row bytes in LDS
    constexpr int KW = KB * 4;          // 16B units per row
    constexpr int U = (32 * KW) / 256;  // 16B units per thread per tile
    __shared__ __align__(16) char sA[32 * RB];
    const _Float16* A16 = (const _Float16*)Av;
    const float* A32 = (const float*)Av;
    const int tid = threadIdx.x;
    const int w = tid >> 6, l = tid & 63;
    const int lm = l & 15, lg = l >> 4;

    h8 wreg[KB][4];
#pragma unroll
    for (int kb = 0; kb < KB; ++kb)
#pragma unroll
        for (int n = 0; n < 4; ++n)
            wreg[kb][n] = *(const h8*)(pWph + (size_t)(kb * 16 + w * 4 + n) * 512 + l * 8);

    float breg[4];
    if constexpr (MODE == 1) {
#pragma unroll
        for (int n = 0; n < 4; ++n) breg[n] = bias[w * 64 + n * 16 + lm];
    }
    float sS[4] = {0.f, 0.f, 0.f, 0.f}, sQ[4] = {0.f, 0.f, 0.f, 0.f};

    const int NT = (NN + 31) / 32;
    int4 pre[U];
    int t = blockIdx.x;
#pragma unroll
    for (int j = 0; j < U; ++j) {
        int unit = tid * U + j;
        int r = unit / KW, s = unit % KW;
        int grow = t * 32 + r;
        int4 z = {0, 0, 0, 0};
        if (grow < NN) {
            if constexpr (SRC32) {
                f4 v0 = *(const f4*)(A32 + (size_t)grow * K + s * 8);
                f4 v1 = *(const f4*)(A32 + (size_t)grow * K + s * 8 + 4);
                h8 h;
                h[0] = (_Float16)v0[0]; h[1] = (_Float16)v0[1];
                h[2] = (_Float16)v0[2]; h[3] = (_Float16)v0[3];
                h[4] = (_Float16)v1[0]; h[5] = (_Float16)v1[1];
                h[6] = (_Float16)v1[2]; h[7] = (_Float16)v1[3];
                pre[j] = *(int4*)&h;
            } else {
                pre[j] = *(const int4*)(A16 + (size_t)grow * K + s * 8);
            }
        } else pre[j] = z;
    }

    for (; t < NT; t += gridDim.x) {
        __syncthreads();
#pragma unroll
        for (int j = 0; j < U; ++j) {
            int unit = tid * U + j;
            int r = unit / KW, s = unit % KW;
            *(int4*)(sA + r * RB + SWZ(r, s * 16)) = pre[j];
        }
        int tn = t + gridDim.x;
        if (tn < NT) {
#pragma unroll
            for (int j = 0; j < U; ++j) {
                int unit = tid * U + j;
                int r = unit / KW, s = unit % KW;
                int grow = tn * 32 + r;
                int4 z = {0, 0, 0, 0};
                if (grow < NN) {
                    if constexpr (SRC32) {
                        f4 v0 = *(const f4*)(A32 + (size_t)grow * K + s * 8);
                        f4 v1 = *(const f4*)(A32 + (size_t)grow * K + s * 8 + 4);
                        h8 h;
                        h[0] = (_Float16)v0[0]; h[1] = (_Float16)v0[1];
                        h[2] = (_Float16)v0[2]; h[3] = (_Float16)v0[3];
                        h[4] = (_Float16)v1[0]; h[5] = (_Float16)v1[1];
                        h[6] = (_Float16)v1[2]; h[7] = (_Float16)v1[3];
                        pre[j] = *(int4*)&h;
                    } else {
                        pre[j] = *(const int4*)(A16 + (size_t)grow * K + s * 8);
                    }
                } else pre[j] = z;
            }
        }
        __syncthreads();

        f4 acc[2][4];
        const f4 z4 = {0.f, 0.f, 0.f, 0.f};
#pragma unroll
        for (int rf = 0; rf < 2; ++rf)
#pragma unroll
            for (int n = 0; n < 4; ++n) acc[rf][n] = z4;

#pragma unroll
        for (int kb = 0; kb < KB; ++kb) {
            h8 a0 = *(const h8*)(sA + lm * RB + SWZ(lm, kb * 64 + lg * 16));
            h8 a1 = *(const h8*)(sA + (16 + lm) * RB + SWZ(16 + lm, kb * 64 + lg * 16));
#pragma unroll
            for (int n = 0; n < 4; ++n) {
                acc[0][n] = __builtin_amdgcn_mfma_f32_16x16x32_f16(a0, wreg[kb][n], acc[0][n], 0, 0, 0);
                acc[1][n] = __builtin_amdgcn_mfma_f32_16x16x32_f16(a1, wreg[kb][n], acc[1][n], 0, 0, 0);
            }
        }

        const int row0 = t * 32;
#pragma unroll
        for (int rf = 0; rf < 2; ++rf)
#pragma unroll
            for (int n = 0; n < 4; ++n) {
                const int col = w * 64 + n * 16 + lm;
#pragma unroll
                for (int q = 0; q < 4; ++q) {
                    int grow = row0 + rf * 16 + lg * 4 + q;
                    if (grow < NN) {
                        float v = acc[rf][n][q];
                        if constexpr (MODE == 1) {
                            v = fmaxf(v + breg[n], 0.f);
                            sS[n] += v;
                            sQ[n] += v * v;
                        }
                        C[(size_t)grow * HH + col] = (_Float16)v;
                    }
                }
            }
    }

    if constexpr (MODE == 1) {
#pragma unroll
        for (int n = 0; n < 4; ++n) {
            float s = sS[n];
            s += __shfl_xor(s, 16); s += __shfl_xor(s, 32);
            float q = sQ[n];
            q += __shfl_xor(q, 16); q += __shfl_xor(q, 32);
            if (lg == 0) {
                atomicAdd(&stats[w * 64 + n * 16 + lm], s);
                atomicAdd(&stats[HH + w * 64 + n * 16 + lm], q);
            }
        }
    }
}

// ---------------- merged phase-B: outB = relu(h_a@(I+Wc1) + hx0@(I+Wc2) + bB) ----------------
// 512 thr (8 waves). Wave w owns cols [w*32, w*32+32) of BOTH GEMMs. In-place C=A1.
__global__ __launch_bounds__(512, 1)
void k_gemmB(const _Float16* __restrict__ A1, const _Float16* __restrict__ A2,
             const _Float16* __restrict__ pW, const float* __restrict__ bB,
             _Float16* __restrict__ C) {
    __shared__ __align__(16) char sA[32768];  // [32][512B] x2
    const int tid = threadIdx.x;
    const int w = tid >> 6, l = tid & 63;
    const int lm = l & 15, lg = l >> 4;

    h8 w1[8][2], w2[8][2];
#pragma unroll
    for (int kb = 0; kb < 8; ++kb)
#pragma unroll
        for (int n = 0; n < 2; ++n) {
            w1[kb][n] = *(const h8*)(pW + OFF_C1 + (size_t)(kb * 16 + w * 2 + n) * 512 + l * 8);
            w2[kb][n] = *(const h8*)(pW + OFF_C2 + (size_t)(kb * 16 + w * 2 + n) * 512 + l * 8);
        }
    float breg[2];
#pragma unroll
    for (int n = 0; n < 2; ++n) breg[n] = bB[w * 32 + n * 16 + lm];

    const int NT = (NN + 31) / 32;
    int4 pre1[2], pre2[2];
    int t = blockIdx.x;
#pragma unroll
    for (int j = 0; j < 2; ++j) {
        int unit = tid * 2 + j;
        int r = unit >> 5, s = unit & 31;
        int grow = t * 32 + r;
        int4 z = {0, 0, 0, 0};
        pre1[j] = (grow < NN) ? *(const int4*)(A1 + (size_t)grow * HH + s * 8) : z;
        pre2[j] = (grow < NN) ? *(const int4*)(A2 + (size_t)grow * HH + s * 8) : z;
    }

    for (; t < NT; t += gridDim.x) {
        __syncthreads();
#pragma unroll
        for (int j = 0; j < 2; ++j) {
            int unit = tid * 2 + j;
            int r = unit >> 5, s = unit & 31;
            *(int4*)(sA + r * 512 + SWZ(r, s * 16)) = pre1[j];
            *(int4*)(sA + 16384 + r * 512 + SWZ(r, s * 16)) = pre2[j];
        }
        int tn = t + gridDim.x;
        if (tn < NT) {
#pragma unroll
            for (int j = 0; j < 2; ++j) {
                int unit = tid * 2 + j;
                int r = unit >> 5, s = unit & 31;
                int grow = tn * 32 + r;
                int4 z = {0, 0, 0, 0};
                pre1[j] = (grow < NN) ? *(const int4*)(A1 + (size_t)grow * HH + s * 8) : z;
                pre2[j] = (grow < NN) ? *(const int4*)(A2 + (size_t)grow * HH + s * 8) : z;
            }
        }
        __syncthreads();

        f4 acc[2][2];
        const f4 z4 = {0.f, 0.f, 0.f, 0.f};
#pragma unroll
        for (int rf = 0; rf < 2; ++rf)
#pragma unroll
            for (int n = 0; n < 2; ++n) acc[rf][n] = z4;

#pragma unroll
        for (int kb = 0; kb < 8; ++kb) {
            h8 a10 = *(const h8*)(sA + lm * 512 + SWZ(lm, kb * 64 + lg * 16));
            h8 a11 = *(const h8*)(sA + (16 + lm) * 512 + SWZ(16 + lm, kb * 64 + lg * 16));
            h8 a20 = *(const h8*)(sA + 16384 + lm * 512 + SWZ(lm, kb * 64 + lg * 16));
            h8 a21 = *(const h8*)(sA + 16384 + (16 + lm) * 512 + SWZ(16 + lm, kb * 64 + lg * 16));
#pragma unroll
            for (int n = 0; n < 2; ++n) {
                acc[0][n] = __builtin_amdgcn_mfma_f32_16x16x32_f16(a10, w1[kb][n], acc[0][n], 0, 0, 0);
                acc[1][n] = __builtin_amdgcn_mfma_f32_16x16x32_f16(a11, w1[kb][n], acc[1][n], 0, 0, 0);
                acc[0][n] = __builtin_amdgcn_mfma_f32_16x16x32_f16(a20, w2[kb][n], acc[0][n], 0, 0, 0);
                acc[1][n] = __builtin_amdgcn_mfma_f32_16x16x32_f16(a21, w2[kb][n], acc[1][n], 0, 0, 0);
            }
        }

        const int row0 = t * 32;
#pragma unroll
        for (int rf = 0; rf < 2; ++rf)
#pragma unroll
            for (int n = 0; n < 2; ++n) {
                const int col = w * 32 + n * 16 + lm;
#pragma unroll
                for (int q = 0; q < 4; ++q) {
                    int grow = row0 + rf * 16 + lg * 4 + q;
                    if (grow < NN) {
                        float v = fmaxf(acc[rf][n][q] + breg[n], 0.f);
                        C[(size_t)grow * HH + col] = (_Float16)v;
                    }
                }
            }
    }
}

// ---------------- BN fold ----------------
__global__ void k_bnprep(const float* __restrict__ stats, const float* __restrict__ gamma,
                         const float* __restrict__ beta, const float* __restrict__ W_f2,
                         const float* __restrict__ b_f2, float* __restrict__ WT,
                         float* __restrict__ bfold) {
    __shared__ float sh[HH];
    const int c = threadIdx.x;
    const float invN = 1.0f / (float)NN;
    float mu = stats[c] * invN;
    float var = stats[HH + c] * invN - mu * mu;
    float scale = gamma[c] * rsqrtf(var + BN_EPS);
    float shift = beta[c] - mu * scale;
    sh[c] = shift;
    for (int j = 0; j < CC; ++j)
        WT[j * HH + c] = scale * W_f2[c * CC + j];
    __syncthreads();
    if (c < CC) {
        float b = b_f2[c];
        for (int k = 0; k < HH; ++k) b += sh[k] * W_f2[k * CC + c];
        bfold[c] = b;
    }
}

// ---------------- final: out = h @ WT^T + bfold (h is fp16) ----------------
__global__ __launch_bounds__(320)
void k_final(const _Float16* __restrict__ bufH, const float* __restrict__ WT,
             const float* __restrict__ bfold, float* __restrict__ out) {
    __shared__ float sH[32 * 260];
    const int tid = threadIdx.x;
    const int row0 = blockIdx.x * 32;
    for (int i = tid; i < 32 * 32; i += 320) {
        int r = i >> 5, c8 = i & 31;
        int gr = row0 + r;
        if (gr >= NN) gr = NN - 1;
        h8 v = *(const h8*)(bufH + (size_t)gr * HH + c8 * 8);
        float* dst = sH + r * 260 + c8 * 8;
#pragma unroll
        for (int jj = 0; jj < 8; ++jj) dst[jj] = (float)v[jj];
    }
    __syncthreads();
    const int c = tid / 8, rl = tid % 8;
    const float bb = bfold[c];
    const float* wt = WT + (size_t)c * HH;
#pragma unroll
    for (int rr = 0; rr < 4; ++rr) {
        int r = rr * 8 + rl;
        int gr = row0 + r;
        float acc = bb;
        const float* hr = sH + r * 260;
#pragma unroll 8
        for (int k = 0; k < HH; k += 4) {
            f4 a = *(const f4*)(hr + k);
            f4 w = *(const f4*)(wt + k);
            acc += a[0] * w[0] + a[1] * w[1] + a[2] * w[2] + a[3] * w[3];
        }
        if (gr < NN) out[(size_t)gr * CC + c] = acc;
    }
}

extern "C" void kernel_launch(void* const* d_in, const int* in_sizes, int n_in,
                              void* d_out, int out_size, void* d_ws, size_t ws_size,
                              hipStream_t stream) {
    const float* x      = (const float*)d_in[0];
    const int*   ei     = (const int*)d_in[1];
    const float* ew     = (const float*)d_in[2];
    const float* W_edge = (const float*)d_in[3];
    const float* b_edge = (const float*)d_in[4];
    const float* W_node = (const float*)d_in[5];
    const float* b_node = (const float*)d_in[6];
    const float* W_c1   = (const float*)d_in[7];
    const float* b_c1   = (const float*)d_in[8];
    const float* W_c2   = (const float*)d_in[9];
    const float* b_c2   = (const float*)d_in[10];
    const float* W_f1   = (const float*)d_in[11];
    const float* b_f1   = (const float*)d_in[12];
    const float* gamma  = (const float*)d_in[13];
    const float* beta   = (const float*)d_in[14];
    const float* W_f2   = (const float*)d_in[15];
    const float* b_f2   = (const float*)d_in[16];
    float* out = (float*)d_out;

    // buf1: hx0 ; buf2: h_a -> outB (in place) ; buf3: h ; W16: fp16 W_edge
    _Float16* buf1 = (_Float16*)d_ws;
    _Float16* buf2 = buf1 + (size_t)NN * HH;
    _Float16* buf3 = buf2 + (size_t)NN * HH;
    _Float16* W16  = buf3 + (size_t)NN * HH;
    float* stats = (float*)(W16 + (size_t)NN * HH);       // 512
    float* bB    = stats + 2 * HH;                        // 256
    float* WT    = bB + HH;                               // C*H
    float* bfold = WT + CC * HH;                          // 64 (pad)
    float* sw    = bfold + 64;                            // E
    int* deg     = (int*)(sw + EE);                       // N
    int* rowptr  = deg + NN;                              // N+1
    int* pos     = rowptr + NN + 1;                       // N
    int* ssrc    = pos + NN;                              // E
    _Float16* pW = (_Float16*)(ssrc + EE);                // 229376 halves
    int* bsums   = (int*)(pW + PW_HALVES);                // 256

    k_init<<<196, 256, 0, stream>>>(stats, deg);
    k_cvtW<<<(NN * HH / 8 + 255) / 256, 256, 0, stream>>>(W_edge, W16);
    k_pack<<<113, 256, 0, stream>>>(W_node, W_c1, W_c2, W_f1, b_node, b_c1, b_c2, pW, bB);
    k_hist<<<(EE + 255) / 256, 256, 0, stream>>>(ei, deg);
    k_scan1<<<196, 256, 0, stream>>>(deg, rowptr, bsums);
    k_scan2<<<1, 256, 0, stream>>>(bsums);
    k_scan3<<<196, 256, 0, stream>>>(rowptr, bsums, pos);
    k_ssort<<<(EE + 255) / 256, 256, 0, stream>>>(ei, ew, pos, ssrc, sw);
    k_gather<<<12500, 256, 0, stream>>>(rowptr, ssrc, sw, W16, b_edge, buf2);

    // GA: hx0 = fp16(x) @ W_node  (K=128, fp32 src) -> buf1
    k_gemm<4, 0, 1><<<512, 256, 0, stream>>>(x, pW + OFF_NODE, nullptr, buf1, nullptr);
    // GB: outB = relu(h_a@(I+Wc1) + hx0@(I+Wc2) + bB) -> buf2 (in place)
    k_gemmB<<<256, 512, 0, stream>>>(buf2, buf1, pW, bB, buf2);
    // GC: h = relu(outB @ W_f1 + b_f1) + BN stats -> buf3
    k_gemm<8, 1, 0><<<512, 256, 0, stream>>>(buf2, pW + OFF_F1, b_f1, buf3, stats);

    k_bnprep<<<1, 256, 0, stream>>>(stats, gamma, beta, W_f2, b_f2, WT, bfold);
    k_final<<<(NN + 31) / 32, 320, 0, stream>>>(buf3, WT, bfold, out);
}

// Round 6
// 287.424 us; speedup vs baseline: 4.1702x; 1.1794x over previous
//
#include <hip/hip_runtime.h>

#define NN 50000
#define EE 800000
#define FF 128
#define HH 256
#define CC 40
#define BN_EPS 1e-5f

typedef float f4 __attribute__((ext_vector_type(4)));
typedef _Float16 h8 __attribute__((ext_vector_type(8)));
typedef _Float16 h4 __attribute__((ext_vector_type(4)));

// packed-weight half offsets: blocks of (kb,nb) -> 512 halves each
#define OFF_NODE 0            // 4*16 units
#define OFF_C1   32768        // 8*16 units
#define OFF_C2   98304
#define OFF_F1   163840
#define PW_HALVES 229376

#define SWZ(row, c2) ((c2) ^ (((row) & 7) << 4))

// ---------------- init: zero stats + degree ----------------
__global__ void k_init(float* __restrict__ stats, int* __restrict__ deg) {
    int i = blockIdx.x * blockDim.x + threadIdx.x;
    if (i < 2 * HH) stats[i] = 0.f;
    if (i < NN) deg[i] = 0;
}

// ---------------- W_edge -> fp16 ----------------
__global__ void k_cvtW(const float* __restrict__ W, _Float16* __restrict__ W16) {
    int i = blockIdx.x * blockDim.x + threadIdx.x;
    if (i < NN * HH / 8) {
        f4 v0 = ((const f4*)W)[i * 2];
        f4 v1 = ((const f4*)W)[i * 2 + 1];
        h8 h;
        h[0] = (_Float16)v0[0]; h[1] = (_Float16)v0[1];
        h[2] = (_Float16)v0[2]; h[3] = (_Float16)v0[3];
        h[4] = (_Float16)v1[0]; h[5] = (_Float16)v1[1];
        h[6] = (_Float16)v1[2]; h[7] = (_Float16)v1[3];
        ((h8*)W16)[i] = h;
    }
}

// ---------------- pack weights into MFMA-B fragment layout (fp16) ----------------
__global__ __launch_bounds__(256)
void k_pack(const float* __restrict__ W_node, const float* __restrict__ W_c1,
            const float* __restrict__ W_c2, const float* __restrict__ W_f1,
            const float* __restrict__ b_node, const float* __restrict__ b_c1,
            const float* __restrict__ b_c2, _Float16* __restrict__ pW,
            float* __restrict__ bB) {
    const int tid = threadIdx.x;
    if (blockIdx.x == 112) {  // combined phase-B bias: b_c1+b_c2+b_node@(I+W_c2)
        int c = tid;
        if (c < HH) {
            float a = 0.f;
            for (int k = 0; k < HH; ++k) a += b_node[k] * W_c2[k * HH + c];
            bB[c] = a + b_node[c] + b_c1[c] + b_c2[c];
        }
        return;
    }
    const int unit = blockIdx.x * 4 + (tid >> 6);
    const int lane = tid & 63, lm = lane & 15, lg = lane >> 4;
    const float* Ws;
    bool addI;
    int u = unit;
    if (u < 64)       { Ws = W_node; addI = false; }
    else if (u < 192) { Ws = W_c1;   addI = true;  u -= 64; }
    else if (u < 320) { Ws = W_c2;   addI = true;  u -= 192; }
    else              { Ws = W_f1;   addI = false; u -= 320; }
    const int kb = u >> 4, nb = u & 15;
    h8 hv;
#pragma unroll
    for (int j = 0; j < 8; ++j) {
        int kr = kb * 32 + lg * 8 + j;
        int col = nb * 16 + lm;
        float v = Ws[kr * HH + col];
        if (addI && kr == col) v += 1.f;
        hv[j] = (_Float16)v;
    }
    *(h8*)(pW + (size_t)unit * 512 + lane * 8) = hv;
}

// ---------------- histogram of dst ----------------
__global__ void k_hist(const int* __restrict__ ei, int* __restrict__ deg) {
    int e = blockIdx.x * blockDim.x + threadIdx.x;
    if (e < EE) atomicAdd(&deg[ei[EE + e]], 1);
}

// ---------------- two-level scan ----------------
__global__ __launch_bounds__(256)
void k_scan1(const int* __restrict__ deg, int* __restrict__ rowptr, int* __restrict__ bsums) {
    __shared__ int t[256];
    const int tid = threadIdx.x;
    int i = blockIdx.x * 256 + tid;
    int v = (i < NN) ? deg[i] : 0;
    t[tid] = v;
    __syncthreads();
#pragma unroll
    for (int off = 1; off < 256; off <<= 1) {
        int u = (tid >= off) ? t[tid - off] : 0;
        __syncthreads();
        t[tid] += u;
        __syncthreads();
    }
    if (i < NN) rowptr[i] = t[tid] - v;
    if (tid == 255) bsums[blockIdx.x] = t[tid];
}
__global__ __launch_bounds__(256)
void k_scan2(int* __restrict__ bsums) {
    __shared__ int t[256];
    const int tid = threadIdx.x;
    int v = (tid < 196) ? bsums[tid] : 0;
    t[tid] = v;
    __syncthreads();
#pragma unroll
    for (int off = 1; off < 256; off <<= 1) {
        int u = (tid >= off) ? t[tid - off] : 0;
        __syncthreads();
        t[tid] += u;
        __syncthreads();
    }
    if (tid < 196) bsums[tid] = t[tid] - v;
}
__global__ __launch_bounds__(256)
void k_scan3(int* __restrict__ rowptr, const int* __restrict__ bsums, int* __restrict__ pos) {
    int i = blockIdx.x * 256 + threadIdx.x;
    if (i < NN) {
        int r = rowptr[i] + bsums[blockIdx.x];
        rowptr[i] = r;
        pos[i] = r;
    }
    if (i == 0) rowptr[NN] = EE;
}

// ---------------- bin-scatter (src, w) into CSR order ----------------
__global__ void k_ssort(const int* __restrict__ ei, const float* __restrict__ ew,
                        int* __restrict__ pos, int* __restrict__ ssrc,
                        float* __restrict__ sw) {
    int e = blockIdx.x * blockDim.x + threadIdx.x;
    if (e < EE) {
        int d = ei[EE + e];
        int p = atomicAdd(&pos[d], 1);
        ssrc[p] = ei[e];
        sw[p] = ew[e];
    }
}

// ---------------- gather-accumulate: one wave per node (fp16 W_edge, unroll 4) ----------------
__global__ __launch_bounds__(256)
void k_gather(const int* __restrict__ rowptr, const int* __restrict__ ssrc,
              const float* __restrict__ sw, const _Float16* __restrict__ W16,
              const float* __restrict__ b_edge, _Float16* __restrict__ bufHA) {
    const int wave = threadIdx.x >> 6;
    const int lane = threadIdx.x & 63;
    const int node = blockIdx.x * 4 + wave;
    if (node >= NN) return;
    const int beg = rowptr[node], end = rowptr[node + 1];
    const int c0 = lane * 4;
    f4 acc = {0.f, 0.f, 0.f, 0.f};
    int e = beg;
    for (; e + 3 < end; e += 4) {
        int s0 = ssrc[e], s1 = ssrc[e + 1], s2 = ssrc[e + 2], s3 = ssrc[e + 3];
        float w0 = sw[e], w1 = sw[e + 1], w2 = sw[e + 2], w3 = sw[e + 3];
        h4 r0 = *(const h4*)(W16 + (size_t)s0 * HH + c0);
        h4 r1 = *(const h4*)(W16 + (size_t)s1 * HH + c0);
        h4 r2 = *(const h4*)(W16 + (size_t)s2 * HH + c0);
        h4 r3 = *(const h4*)(W16 + (size_t)s3 * HH + c0);
        f4 f0 = {(float)r0[0], (float)r0[1], (float)r0[2], (float)r0[3]};
        f4 f1 = {(float)r1[0], (float)r1[1], (float)r1[2], (float)r1[3]};
        f4 f2 = {(float)r2[0], (float)r2[1], (float)r2[2], (float)r2[3]};
        f4 f3 = {(float)r3[0], (float)r3[1], (float)r3[2], (float)r3[3]};
        acc += w0 * f0 + w1 * f1 + w2 * f2 + w3 * f3;
    }
    for (; e < end; ++e) {
        h4 r0 = *(const h4*)(W16 + (size_t)ssrc[e] * HH + c0);
        f4 f0 = {(float)r0[0], (float)r0[1], (float)r0[2], (float)r0[3]};
        acc += sw[e] * f0;
    }
    f4 b = *(const f4*)(b_edge + c0);
    acc += b;
    h4 hv;
    hv[0] = (_Float16)acc[0]; hv[1] = (_Float16)acc[1];
    hv[2] = (_Float16)acc[2]; hv[3] = (_Float16)acc[3];
    *(h4*)(bufHA + (size_t)node * HH + c0) = hv;
}

// ---------------- weight-stationary streaming GEMM (single matrix) ----------------
// block = 256 thr (4 waves). Wave w owns output cols [w*64, w*64+64).
// MODE: 0 = plain store, 1 = relu(acc+bias) + BN stats. SRC32: A is fp32.
template <int KB, int MODE, int SRC32>
__global__ __launch_bounds__(256, 2)
void k_gemm(const void* __restrict__ Av, const _Float16* __restrict__ pWph,
            const float* __restrict__ bias, _Float16* __restrict__ C,
            float* __restrict__ stats) {
    constexpr int K = KB * 32;
    constexpr int RB = K * 2;           // row bytes in LDS
    constexpr int KW = KB * 4;          // 16B units per row
    constexpr int U = (32 * KW) / 256;  // 16B units per thread per tile
    __shared__ __align__(16) char sA[32 * RB];
    const _Float16* A16 = (const _Float16*)Av;
    const float* A32 = (const float*)Av;
    const int tid = threadIdx.x;
    const int w = tid >> 6, l = tid & 63;
    const int lm = l & 15, lg = l >> 4;

    h8 wreg[KB][4];
#pragma unroll
    for (int kb = 0; kb < KB; ++kb)
#pragma unroll
        for (int n = 0; n < 4; ++n)
            wreg[kb][n] = *(const h8*)(pWph + (size_t)(kb * 16 + w * 4 + n) * 512 + l * 8);

    float breg[4];
    if constexpr (MODE == 1) {
#pragma unroll
        for (int n = 0; n < 4; ++n) breg[n] = bias[w * 64 + n * 16 + lm];
    }
    float sS[4] = {0.f, 0.f, 0.f, 0.f}, sQ[4] = {0.f, 0.f, 0.f, 0.f};

    const int NT = (NN + 31) / 32;
    int4 pre[U];
    int t = blockIdx.x;
#pragma unroll
    for (int j = 0; j < U; ++j) {
        int unit = tid * U + j;
        int r = unit / KW, s = unit % KW;
        int grow = t * 32 + r;
        int4 z = {0, 0, 0, 0};
        if (grow < NN) {
            if constexpr (SRC32) {
                f4 v0 = *(const f4*)(A32 + (size_t)grow * K + s * 8);
                f4 v1 = *(const f4*)(A32 + (size_t)grow * K + s * 8 + 4);
                h8 h;
                h[0] = (_Float16)v0[0]; h[1] = (_Float16)v0[1];
                h[2] = (_Float16)v0[2]; h[3] = (_Float16)v0[3];
                h[4] = (_Float16)v1[0]; h[5] = (_Float16)v1[1];
                h[6] = (_Float16)v1[2]; h[7] = (_Float16)v1[3];
                pre[j] = *(int4*)&h;
            } else {
                pre[j] = *(const int4*)(A16 + (size_t)grow * K + s * 8);
            }
        } else pre[j] = z;
    }

    for (; t < NT; t += gridDim.x) {
        __syncthreads();
#pragma unroll
        for (int j = 0; j < U; ++j) {
            int unit = tid * U + j;
            int r = unit / KW, s = unit % KW;
            *(int4*)(sA + r * RB + SWZ(r, s * 16)) = pre[j];
        }
        int tn = t + gridDim.x;
        if (tn < NT) {
#pragma unroll
            for (int j = 0; j < U; ++j) {
                int unit = tid * U + j;
                int r = unit / KW, s = unit % KW;
                int grow = tn * 32 + r;
                int4 z = {0, 0, 0, 0};
                if (grow < NN) {
                    if constexpr (SRC32) {
                        f4 v0 = *(const f4*)(A32 + (size_t)grow * K + s * 8);
                        f4 v1 = *(const f4*)(A32 + (size_t)grow * K + s * 8 + 4);
                        h8 h;
                        h[0] = (_Float16)v0[0]; h[1] = (_Float16)v0[1];
                        h[2] = (_Float16)v0[2]; h[3] = (_Float16)v0[3];
                        h[4] = (_Float16)v1[0]; h[5] = (_Float16)v1[1];
                        h[6] = (_Float16)v1[2]; h[7] = (_Float16)v1[3];
                        pre[j] = *(int4*)&h;
                    } else {
                        pre[j] = *(const int4*)(A16 + (size_t)grow * K + s * 8);
                    }
                } else pre[j] = z;
            }
        }
        __syncthreads();

        f4 acc[2][4];
        const f4 z4 = {0.f, 0.f, 0.f, 0.f};
#pragma unroll
        for (int rf = 0; rf < 2; ++rf)
#pragma unroll
            for (int n = 0; n < 4; ++n) acc[rf][n] = z4;

#pragma unroll
        for (int kb = 0; kb < KB; ++kb) {
            h8 a0 = *(const h8*)(sA + lm * RB + SWZ(lm, kb * 64 + lg * 16));
            h8 a1 = *(const h8*)(sA + (16 + lm) * RB + SWZ(16 + lm, kb * 64 + lg * 16));
#pragma unroll
            for (int n = 0; n < 4; ++n) {
                acc[0][n] = __builtin_amdgcn_mfma_f32_16x16x32_f16(a0, wreg[kb][n], acc[0][n], 0, 0, 0);
                acc[1][n] = __builtin_amdgcn_mfma_f32_16x16x32_f16(a1, wreg[kb][n], acc[1][n], 0, 0, 0);
            }
        }

        const int row0 = t * 32;
#pragma unroll
        for (int rf = 0; rf < 2; ++rf)
#pragma unroll
            for (int n = 0; n < 4; ++n) {
                const int col = w * 64 + n * 16 + lm;
#pragma unroll
                for (int q = 0; q < 4; ++q) {
                    int grow = row0 + rf * 16 + lg * 4 + q;
                    if (grow < NN) {
                        float v = acc[rf][n][q];
                        if constexpr (MODE == 1) {
                            v = fmaxf(v + breg[n], 0.f);
                            sS[n] += v;
                            sQ[n] += v * v;
                        }
                        C[(size_t)grow * HH + col] = (_Float16)v;
                    }
                }
            }
    }

    if constexpr (MODE == 1) {
#pragma unroll
        for (int n = 0; n < 4; ++n) {
            float s = sS[n];
            s += __shfl_xor(s, 16); s += __shfl_xor(s, 32);
            float q = sQ[n];
            q += __shfl_xor(q, 16); q += __shfl_xor(q, 32);
            if (lg == 0) {
                atomicAdd(&stats[w * 64 + n * 16 + lm], s);
                atomicAdd(&stats[HH + w * 64 + n * 16 + lm], q);
            }
        }
    }
}

// ---------------- merged phase-B: outB = relu(h_a@(I+Wc1) + hx0@(I+Wc2) + bB) ----------------
// 512 thr (8 waves). Wave w owns cols [w*32, w*32+32) of BOTH GEMMs. In-place C=A1.
__global__ __launch_bounds__(512, 1)
void k_gemmB(const _Float16* __restrict__ A1, const _Float16* __restrict__ A2,
             const _Float16* __restrict__ pW, const float* __restrict__ bB,
             _Float16* __restrict__ C) {
    __shared__ __align__(16) char sA[32768];  // [32][512B] x2
    const int tid = threadIdx.x;
    const int w = tid >> 6, l = tid & 63;
    const int lm = l & 15, lg = l >> 4;

    h8 w1[8][2], w2[8][2];
#pragma unroll
    for (int kb = 0; kb < 8; ++kb)
#pragma unroll
        for (int n = 0; n < 2; ++n) {
            w1[kb][n] = *(const h8*)(pW + OFF_C1 + (size_t)(kb * 16 + w * 2 + n) * 512 + l * 8);
            w2[kb][n] = *(const h8*)(pW + OFF_C2 + (size_t)(kb * 16 + w * 2 + n) * 512 + l * 8);
        }
    float breg[2];
#pragma unroll
    for (int n = 0; n < 2; ++n) breg[n] = bB[w * 32 + n * 16 + lm];

    const int NT = (NN + 31) / 32;
    int4 pre1[2], pre2[2];
    int t = blockIdx.x;
#pragma unroll
    for (int j = 0; j < 2; ++j) {
        int unit = tid * 2 + j;
        int r = unit >> 5, s = unit & 31;
        int grow = t * 32 + r;
        int4 z = {0, 0, 0, 0};
        pre1[j] = (grow < NN) ? *(const int4*)(A1 + (size_t)grow * HH + s * 8) : z;
        pre2[j] = (grow < NN) ? *(const int4*)(A2 + (size_t)grow * HH + s * 8) : z;
    }

    for (; t < NT; t += gridDim.x) {
        __syncthreads();
#pragma unroll
        for (int j = 0; j < 2; ++j) {
            int unit = tid * 2 + j;
            int r = unit >> 5, s = unit & 31;
            *(int4*)(sA + r * 512 + SWZ(r, s * 16)) = pre1[j];
            *(int4*)(sA + 16384 + r * 512 + SWZ(r, s * 16)) = pre2[j];
        }
        int tn = t + gridDim.x;
        if (tn < NT) {
#pragma unroll
            for (int j = 0; j < 2; ++j) {
                int unit = tid * 2 + j;
                int r = unit >> 5, s = unit & 31;
                int grow = tn * 32 + r;
                int4 z = {0, 0, 0, 0};
                pre1[j] = (grow < NN) ? *(const int4*)(A1 + (size_t)grow * HH + s * 8) : z;
                pre2[j] = (grow < NN) ? *(const int4*)(A2 + (size_t)grow * HH + s * 8) : z;
            }
        }
        __syncthreads();

        f4 acc[2][2];
        const f4 z4 = {0.f, 0.f, 0.f, 0.f};
#pragma unroll
        for (int rf = 0; rf < 2; ++rf)
#pragma unroll
            for (int n = 0; n < 2; ++n) acc[rf][n] = z4;

#pragma unroll
        for (int kb = 0; kb < 8; ++kb) {
            h8 a10 = *(const h8*)(sA + lm * 512 + SWZ(lm, kb * 64 + lg * 16));
            h8 a11 = *(const h8*)(sA + (16 + lm) * 512 + SWZ(16 + lm, kb * 64 + lg * 16));
            h8 a20 = *(const h8*)(sA + 16384 + lm * 512 + SWZ(lm, kb * 64 + lg * 16));
            h8 a21 = *(const h8*)(sA + 16384 + (16 + lm) * 512 + SWZ(16 + lm, kb * 64 + lg * 16));
#pragma unroll
            for (int n = 0; n < 2; ++n) {
                acc[0][n] = __builtin_amdgcn_mfma_f32_16x16x32_f16(a10, w1[kb][n], acc[0][n], 0, 0, 0);
                acc[1][n] = __builtin_amdgcn_mfma_f32_16x16x32_f16(a11, w1[kb][n], acc[1][n], 0, 0, 0);
                acc[0][n] = __builtin_amdgcn_mfma_f32_16x16x32_f16(a20, w2[kb][n], acc[0][n], 0, 0, 0);
                acc[1][n] = __builtin_amdgcn_mfma_f32_16x16x32_f16(a21, w2[kb][n], acc[1][n], 0, 0, 0);
            }
        }

        const int row0 = t * 32;
#pragma unroll
        for (int rf = 0; rf < 2; ++rf)
#pragma unroll
            for (int n = 0; n < 2; ++n) {
                const int col = w * 32 + n * 16 + lm;
#pragma unroll
                for (int q = 0; q < 4; ++q) {
                    int grow = row0 + rf * 16 + lg * 4 + q;
                    if (grow < NN) {
                        float v = fmaxf(acc[rf][n][q] + breg[n], 0.f);
                        C[(size_t)grow * HH + col] = (_Float16)v;
                    }
                }
            }
    }
}

// ---------------- BN fold + pack final weights into MFMA-B fragments ----------------
__global__ __launch_bounds__(256)
void k_bnprep(const float* __restrict__ stats, const float* __restrict__ gamma,
              const float* __restrict__ beta, const float* __restrict__ W_f2,
              const float* __restrict__ b_f2, _Float16* __restrict__ pWf,
              float* __restrict__ bfold) {
    __shared__ float sh[HH];      // shift
    __shared__ float ssc[HH];     // scale
    const int tid = threadIdx.x;
    const float invN = 1.0f / (float)NN;
    {
        float mu = stats[tid] * invN;
        float var = stats[HH + tid] * invN - mu * mu;
        float scale = gamma[tid] * rsqrtf(var + BN_EPS);
        sh[tid] = beta[tid] - mu * scale;
        ssc[tid] = scale;
    }
    __syncthreads();
    // bfold
    if (tid < CC) {
        float b = b_f2[tid];
        for (int k = 0; k < HH; ++k) b += sh[k] * W_f2[k * CC + tid];
        bfold[tid] = b;
    }
    // pack scale*W_f2 into 24 fragment units (kb 0..7, nb 0..2), cols>=40 zero
    const int w = tid >> 6, l = tid & 63;
    const int lm = l & 15, lg = l >> 4;
#pragma unroll
    for (int i = 0; i < 6; ++i) {
        int u = w + i * 4;  // 0..23
        int kb = u / 3, nb = u % 3;
        h8 hv;
#pragma unroll
        for (int j = 0; j < 8; ++j) {
            int k = kb * 32 + lg * 8 + j;
            int c = nb * 16 + lm;
            float v = (c < CC) ? ssc[k] * W_f2[k * CC + c] : 0.f;
            hv[j] = (_Float16)v;
        }
        *(h8*)(pWf + (size_t)u * 512 + l * 8) = hv;
    }
}

// ---------------- final via MFMA: out = h @ (scale*W_f2) + bfold ----------------
// 64-row tiles, 4 waves; wave w owns rows w*16..w*16+16, all 48 (40) cols.
__global__ __launch_bounds__(256)
void k_finalM(const _Float16* __restrict__ h, const _Float16* __restrict__ pWf,
              const float* __restrict__ bfold, float* __restrict__ out) {
    __shared__ __align__(16) char sA[64 * 512];
    const int tid = threadIdx.x;
    const int w = tid >> 6, l = tid & 63;
    const int lm = l & 15, lg = l >> 4;

    h8 wreg[8][3];
#pragma unroll
    for (int kb = 0; kb < 8; ++kb)
#pragma unroll
        for (int nb = 0; nb < 3; ++nb)
            wreg[kb][nb] = *(const h8*)(pWf + (size_t)(kb * 3 + nb) * 512 + l * 8);

    const int row0 = blockIdx.x * 64;
#pragma unroll
    for (int j = 0; j < 8; ++j) {
        int unit = tid * 8 + j;
        int r = unit >> 5, s = unit & 31;
        int grow = row0 + r;
        int4 z = {0, 0, 0, 0};
        int4 v = (grow < NN) ? *(const int4*)(h + (size_t)grow * HH + s * 8) : z;
        *(int4*)(sA + r * 512 + SWZ(r, s * 16)) = v;
    }
    __syncthreads();

    f4 acc[3];
    const f4 z4 = {0.f, 0.f, 0.f, 0.f};
#pragma unroll
    for (int nb = 0; nb < 3; ++nb) acc[nb] = z4;

    const int ar = w * 16 + lm;
#pragma unroll
    for (int kb = 0; kb < 8; ++kb) {
        h8 a = *(const h8*)(sA + ar * 512 + SWZ(ar, kb * 64 + lg * 16));
#pragma unroll
        for (int nb = 0; nb < 3; ++nb)
            acc[nb] = __builtin_amdgcn_mfma_f32_16x16x32_f16(a, wreg[kb][nb], acc[nb], 0, 0, 0);
    }

#pragma unroll
    for (int nb = 0; nb < 3; ++nb) {
        int col = nb * 16 + lm;
        if (col < CC) {
            float bb = bfold[col];
#pragma unroll
            for (int q = 0; q < 4; ++q) {
                int grow = row0 + w * 16 + lg * 4 + q;
                if (grow < NN) out[(size_t)grow * CC + col] = acc[nb][q] + bb;
            }
        }
    }
}

extern "C" void kernel_launch(void* const* d_in, const int* in_sizes, int n_in,
                              void* d_out, int out_size, void* d_ws, size_t ws_size,
                              hipStream_t stream) {
    const float* x      = (const float*)d_in[0];
    const int*   ei     = (const int*)d_in[1];
    const float* ew     = (const float*)d_in[2];
    const float* W_edge = (const float*)d_in[3];
    const float* b_edge = (const float*)d_in[4];
    const float* W_node = (const float*)d_in[5];
    const float* b_node = (const float*)d_in[6];
    const float* W_c1   = (const float*)d_in[7];
    const float* b_c1   = (const float*)d_in[8];
    const float* W_c2   = (const float*)d_in[9];
    const float* b_c2   = (const float*)d_in[10];
    const float* W_f1   = (const float*)d_in[11];
    const float* b_f1   = (const float*)d_in[12];
    const float* gamma  = (const float*)d_in[13];
    const float* beta   = (const float*)d_in[14];
    const float* W_f2   = (const float*)d_in[15];
    const float* b_f2   = (const float*)d_in[16];
    float* out = (float*)d_out;

    // buf1: hx0 ; buf2: h_a -> outB (in place) ; buf3: h ; W16: fp16 W_edge
    _Float16* buf1 = (_Float16*)d_ws;
    _Float16* buf2 = buf1 + (size_t)NN * HH;
    _Float16* buf3 = buf2 + (size_t)NN * HH;
    _Float16* W16  = buf3 + (size_t)NN * HH;
    float* stats = (float*)(W16 + (size_t)NN * HH);       // 512
    float* bB    = stats + 2 * HH;                        // 256
    float* bfold = bB + HH;                               // 64
    _Float16* pWf = (_Float16*)(bfold + 64);              // 24*512 halves
    float* sw    = (float*)(pWf + 24 * 512);              // E
    int* deg     = (int*)(sw + EE);                       // N
    int* rowptr  = deg + NN;                              // N+1
    int* pos     = rowptr + NN + 1;                       // N
    int* ssrc    = pos + NN;                              // E
    _Float16* pW = (_Float16*)(ssrc + EE);                // 229376 halves
    int* bsums   = (int*)(pW + PW_HALVES);                // 256

    k_init<<<196, 256, 0, stream>>>(stats, deg);
    k_cvtW<<<(NN * HH / 8 + 255) / 256, 256, 0, stream>>>(W_edge, W16);
    k_pack<<<113, 256, 0, stream>>>(W_node, W_c1, W_c2, W_f1, b_node, b_c1, b_c2, pW, bB);
    k_hist<<<(EE + 255) / 256, 256, 0, stream>>>(ei, deg);
    k_scan1<<<196, 256, 0, stream>>>(deg, rowptr, bsums);
    k_scan2<<<1, 256, 0, stream>>>(bsums);
    k_scan3<<<196, 256, 0, stream>>>(rowptr, bsums, pos);
    k_ssort<<<(EE + 255) / 256, 256, 0, stream>>>(ei, ew, pos, ssrc, sw);
    k_gather<<<12500, 256, 0, stream>>>(rowptr, ssrc, sw, W16, b_edge, buf2);

    // GA: hx0 = fp16(x) @ W_node  (K=128, fp32 src) -> buf1
    k_gemm<4, 0, 1><<<512, 256, 0, stream>>>(x, pW + OFF_NODE, nullptr, buf1, nullptr);
    // GB: outB = relu(h_a@(I+Wc1) + hx0@(I+Wc2) + bB) -> buf2 (in place)
    k_gemmB<<<256, 512, 0, stream>>>(buf2, buf1, pW, bB, buf2);
    // GC: h = relu(outB @ W_f1 + b_f1) + BN stats -> buf3
    k_gemm<8, 1, 0><<<512, 256, 0, stream>>>(buf2, pW + OFF_F1, b_f1, buf3, stats);

    k_bnprep<<<1, 256, 0, stream>>>(stats, gamma, beta, W_f2, b_f2, pWf, bfold);
    k_finalM<<<(NN + 63) / 64, 256, 0, stream>>>(buf3, pWf, bfold, out);
}

// Round 7
// 269.633 us; speedup vs baseline: 4.4453x; 1.0660x over previous
//
#include <hip/hip_runtime.h>

#define NN 50000
#define EE 800000
#define FF 128
#define HH 256
#define CC 40
#define BN_EPS 1e-5f

typedef float f4 __attribute__((ext_vector_type(4)));
typedef _Float16 h8 __attribute__((ext_vector_type(8)));
typedef _Float16 h4 __attribute__((ext_vector_type(4)));

#define OFF_NODE 0            // 4*16 units
#define OFF_C1   32768        // 8*16 units
#define OFF_C2   98304
#define OFF_F1   163840
#define PW_HALVES 229376

#define SWZ(row, c2) ((c2) ^ (((row) & 7) << 4))

// ---------------- init: zero stats + degree ----------------
__global__ void k_init(float* __restrict__ stats, int* __restrict__ deg) {
    int i = blockIdx.x * blockDim.x + threadIdx.x;
    if (i < 2 * HH) stats[i] = 0.f;
    if (i < NN) deg[i] = 0;
}

// ---------------- prep: W_edge -> fp16  +  histogram of dst ----------------
__global__ __launch_bounds__(256)
void k_prep(const float* __restrict__ W, _Float16* __restrict__ W16,
            const int* __restrict__ ei, int* __restrict__ deg) {
    const int gsz = gridDim.x * blockDim.x;
    const int i0 = blockIdx.x * blockDim.x + threadIdx.x;
    for (int j = i0; j < NN * HH / 8; j += gsz) {
        f4 v0 = ((const f4*)W)[j * 2];
        f4 v1 = ((const f4*)W)[j * 2 + 1];
        h8 h;
        h[0] = (_Float16)v0[0]; h[1] = (_Float16)v0[1];
        h[2] = (_Float16)v0[2]; h[3] = (_Float16)v0[3];
        h[4] = (_Float16)v1[0]; h[5] = (_Float16)v1[1];
        h[6] = (_Float16)v1[2]; h[7] = (_Float16)v1[3];
        ((h8*)W16)[j] = h;
    }
    for (int e = i0; e < EE; e += gsz) atomicAdd(&deg[ei[EE + e]], 1);
}

// ---------------- pack weights into MFMA-B fragment layout (fp16) ----------------
__global__ __launch_bounds__(256)
void k_pack(const float* __restrict__ W_node, const float* __restrict__ W_c1,
            const float* __restrict__ W_c2, const float* __restrict__ W_f1,
            const float* __restrict__ b_node, const float* __restrict__ b_c1,
            const float* __restrict__ b_c2, _Float16* __restrict__ pW,
            float* __restrict__ bB) {
    const int tid = threadIdx.x;
    if (blockIdx.x == 112) {  // combined phase-B bias: b_c1+b_c2+b_node@(I+W_c2)
        int c = tid;
        if (c < HH) {
            float a = 0.f;
            for (int k = 0; k < HH; ++k) a += b_node[k] * W_c2[k * HH + c];
            bB[c] = a + b_node[c] + b_c1[c] + b_c2[c];
        }
        return;
    }
    const int unit = blockIdx.x * 4 + (tid >> 6);
    const int lane = tid & 63, lm = lane & 15, lg = lane >> 4;
    const float* Ws;
    bool addI;
    int u = unit;
    if (u < 64)       { Ws = W_node; addI = false; }
    else if (u < 192) { Ws = W_c1;   addI = true;  u -= 64; }
    else if (u < 320) { Ws = W_c2;   addI = true;  u -= 192; }
    else              { Ws = W_f1;   addI = false; u -= 320; }
    const int kb = u >> 4, nb = u & 15;
    h8 hv;
#pragma unroll
    for (int j = 0; j < 8; ++j) {
        int kr = kb * 32 + lg * 8 + j;
        int col = nb * 16 + lm;
        float v = Ws[kr * HH + col];
        if (addI && kr == col) v += 1.f;
        hv[j] = (_Float16)v;
    }
    *(h8*)(pW + (size_t)unit * 512 + lane * 8) = hv;
}

// ---------------- two-level scan ----------------
__global__ __launch_bounds__(256)
void k_scan1(const int* __restrict__ deg, int* __restrict__ rowptr, int* __restrict__ bsums) {
    __shared__ int t[256];
    const int tid = threadIdx.x;
    int i = blockIdx.x * 256 + tid;
    int v = (i < NN) ? deg[i] : 0;
    t[tid] = v;
    __syncthreads();
#pragma unroll
    for (int off = 1; off < 256; off <<= 1) {
        int u = (tid >= off) ? t[tid - off] : 0;
        __syncthreads();
        t[tid] += u;
        __syncthreads();
    }
    if (i < NN) rowptr[i] = t[tid] - v;
    if (tid == 255) bsums[blockIdx.x] = t[tid];
}
__global__ __launch_bounds__(256)
void k_scan2(int* __restrict__ bsums) {
    __shared__ int t[256];
    const int tid = threadIdx.x;
    int v = (tid < 196) ? bsums[tid] : 0;
    t[tid] = v;
    __syncthreads();
#pragma unroll
    for (int off = 1; off < 256; off <<= 1) {
        int u = (tid >= off) ? t[tid - off] : 0;
        __syncthreads();
        t[tid] += u;
        __syncthreads();
    }
    if (tid < 196) bsums[tid] = t[tid] - v;
}
__global__ __launch_bounds__(256)
void k_scan3(int* __restrict__ rowptr, const int* __restrict__ bsums, int* __restrict__ pos) {
    int i = blockIdx.x * 256 + threadIdx.x;
    if (i < NN) {
        int r = rowptr[i] + bsums[blockIdx.x];
        rowptr[i] = r;
        pos[i] = r;
    }
    if (i == 0) rowptr[NN] = EE;
}

// ---------------- bin-scatter (src, w) combined 8B into CSR order ----------------
__global__ void k_ssort(const int* __restrict__ ei, const float* __restrict__ ew,
                        int* __restrict__ pos, int2* __restrict__ esw) {
    int e = blockIdx.x * blockDim.x + threadIdx.x;
    if (e < EE) {
        int d = ei[EE + e];
        int p = atomicAdd(&pos[d], 1);
        int2 v;
        v.x = ei[e];
        v.y = __float_as_int(ew[e]);
        esw[p] = v;
    }
}

// ---------------- gather-accumulate: one wave per node, unroll 8 ----------------
__global__ __launch_bounds__(256)
void k_gather(const int* __restrict__ rowptr, const int2* __restrict__ esw,
              const _Float16* __restrict__ W16, const float* __restrict__ b_edge,
              _Float16* __restrict__ outHA) {
    const int wave = threadIdx.x >> 6;
    const int lane = threadIdx.x & 63;
    const int node = blockIdx.x * 4 + wave;
    if (node >= NN) return;
    int e = rowptr[node];
    const int end = rowptr[node + 1];
    const int c0 = lane * 4;
    f4 acc0 = {0.f, 0.f, 0.f, 0.f}, acc1 = {0.f, 0.f, 0.f, 0.f};
    for (; e + 7 < end; e += 8) {
        int2 v[8];
        h4 r[8];
#pragma unroll
        for (int j = 0; j < 8; ++j) v[j] = esw[e + j];
#pragma unroll
        for (int j = 0; j < 8; ++j)
            r[j] = *(const h4*)(W16 + (size_t)v[j].x * HH + c0);
#pragma unroll
        for (int j = 0; j < 8; j += 2) {
            float w0 = __int_as_float(v[j].y);
            float w1 = __int_as_float(v[j + 1].y);
            f4 f0 = {(float)r[j][0], (float)r[j][1], (float)r[j][2], (float)r[j][3]};
            f4 f1 = {(float)r[j + 1][0], (float)r[j + 1][1], (float)r[j + 1][2], (float)r[j + 1][3]};
            acc0 += w0 * f0;
            acc1 += w1 * f1;
        }
    }
    for (; e < end; ++e) {
        int2 v = esw[e];
        h4 rr = *(const h4*)(W16 + (size_t)v.x * HH + c0);
        f4 ff = {(float)rr[0], (float)rr[1], (float)rr[2], (float)rr[3]};
        acc0 += __int_as_float(v.y) * ff;
    }
    f4 b = *(const f4*)(b_edge + c0);
    f4 acc = acc0 + acc1 + b;
    h4 hv;
    hv[0] = (_Float16)acc[0]; hv[1] = (_Float16)acc[1];
    hv[2] = (_Float16)acc[2]; hv[3] = (_Float16)acc[3];
    *(h4*)(outHA + (size_t)node * HH + c0) = hv;
}

// ---------------- weight-stationary streaming GEMM (single matrix) ----------------
// MODE: 0 = plain store, 1 = relu(acc+bias) + BN stats.
template <int KB, int MODE>
__global__ __launch_bounds__(256, 2)
void k_gemm(const _Float16* __restrict__ A16, const _Float16* __restrict__ pWph,
            const float* __restrict__ bias, _Float16* __restrict__ C,
            float* __restrict__ stats) {
    constexpr int K = KB * 32;
    constexpr int RB = K * 2;
    constexpr int KW = KB * 4;
    constexpr int U = (32 * KW) / 256;
    __shared__ __align__(16) char sA[32 * RB];
    const int tid = threadIdx.x;
    const int w = tid >> 6, l = tid & 63;
    const int lm = l & 15, lg = l >> 4;

    h8 wreg[KB][4];
#pragma unroll
    for (int kb = 0; kb < KB; ++kb)
#pragma unroll
        for (int n = 0; n < 4; ++n)
            wreg[kb][n] = *(const h8*)(pWph + (size_t)(kb * 16 + w * 4 + n) * 512 + l * 8);

    float breg[4];
    if constexpr (MODE == 1) {
#pragma unroll
        for (int n = 0; n < 4; ++n) breg[n] = bias[w * 64 + n * 16 + lm];
    }
    float sS[4] = {0.f, 0.f, 0.f, 0.f}, sQ[4] = {0.f, 0.f, 0.f, 0.f};

    const int NT = (NN + 31) / 32;
    int4 pre[U];
    int t = blockIdx.x;
#pragma unroll
    for (int j = 0; j < U; ++j) {
        int unit = tid * U + j;
        int r = unit / KW, s = unit % KW;
        int grow = t * 32 + r;
        int4 z = {0, 0, 0, 0};
        pre[j] = (grow < NN) ? *(const int4*)(A16 + (size_t)grow * K + s * 8) : z;
    }

    for (; t < NT; t += gridDim.x) {
        __syncthreads();
#pragma unroll
        for (int j = 0; j < U; ++j) {
            int unit = tid * U + j;
            int r = unit / KW, s = unit % KW;
            *(int4*)(sA + r * RB + SWZ(r, s * 16)) = pre[j];
        }
        int tn = t + gridDim.x;
        if (tn < NT) {
#pragma unroll
            for (int j = 0; j < U; ++j) {
                int unit = tid * U + j;
                int r = unit / KW, s = unit % KW;
                int grow = tn * 32 + r;
                int4 z = {0, 0, 0, 0};
                pre[j] = (grow < NN) ? *(const int4*)(A16 + (size_t)grow * K + s * 8) : z;
            }
        }
        __syncthreads();

        f4 acc[2][4];
        const f4 z4 = {0.f, 0.f, 0.f, 0.f};
#pragma unroll
        for (int rf = 0; rf < 2; ++rf)
#pragma unroll
            for (int n = 0; n < 4; ++n) acc[rf][n] = z4;

#pragma unroll
        for (int kb = 0; kb < KB; ++kb) {
            h8 a0 = *(const h8*)(sA + lm * RB + SWZ(lm, kb * 64 + lg * 16));
            h8 a1 = *(const h8*)(sA + (16 + lm) * RB + SWZ(16 + lm, kb * 64 + lg * 16));
#pragma unroll
            for (int n = 0; n < 4; ++n) {
                acc[0][n] = __builtin_amdgcn_mfma_f32_16x16x32_f16(a0, wreg[kb][n], acc[0][n], 0, 0, 0);
                acc[1][n] = __builtin_amdgcn_mfma_f32_16x16x32_f16(a1, wreg[kb][n], acc[1][n], 0, 0, 0);
            }
        }

        const int row0 = t * 32;
#pragma unroll
        for (int rf = 0; rf < 2; ++rf)
#pragma unroll
            for (int n = 0; n < 4; ++n) {
                const int col = w * 64 + n * 16 + lm;
#pragma unroll
                for (int q = 0; q < 4; ++q) {
                    int grow = row0 + rf * 16 + lg * 4 + q;
                    if (grow < NN) {
                        float v = acc[rf][n][q];
                        if constexpr (MODE == 1) {
                            v = fmaxf(v + breg[n], 0.f);
                            sS[n] += v;
                            sQ[n] += v * v;
                        }
                        C[(size_t)grow * HH + col] = (_Float16)v;
                    }
                }
            }
    }

    if constexpr (MODE == 1) {
#pragma unroll
        for (int n = 0; n < 4; ++n) {
            float s = sS[n];
            s += __shfl_xor(s, 16); s += __shfl_xor(s, 32);
            float q = sQ[n];
            q += __shfl_xor(q, 16); q += __shfl_xor(q, 32);
            if (lg == 0) {
                atomicAdd(&stats[w * 64 + n * 16 + lm], s);
                atomicAdd(&stats[HH + w * 64 + n * 16 + lm], q);
            }
        }
    }
}

// ---------------- fused phase A+B: outB = relu(h_a@(I+Wc1) + (x@Wn)@(I+Wc2) + bB) ----------------
// 512 thr (8 waves). Wave w owns output cols [w*32, w*32+32). In-place C = A1.
// LDS: sX fp16 [32][256B] @0 (8KB) ; sA1 [32][512B] @8192 (16KB) ; sHX [32][512B] @24576 (16KB)
__global__ __launch_bounds__(512, 1)
void k_gemmB2(const float* __restrict__ x, const _Float16* __restrict__ A1,
              const _Float16* __restrict__ pW, const float* __restrict__ bB,
              _Float16* __restrict__ C) {
    __shared__ __align__(16) char sm[40960];
    const int tid = threadIdx.x;
    const int w = tid >> 6, l = tid & 63;
    const int lm = l & 15, lg = l >> 4;
    const int rx = tid >> 4, sx = tid & 15;

    h8 w1[8][2], w2[8][2], wn[4][2];
#pragma unroll
    for (int kb = 0; kb < 8; ++kb)
#pragma unroll
        for (int n = 0; n < 2; ++n) {
            w1[kb][n] = *(const h8*)(pW + OFF_C1 + (size_t)(kb * 16 + w * 2 + n) * 512 + l * 8);
            w2[kb][n] = *(const h8*)(pW + OFF_C2 + (size_t)(kb * 16 + w * 2 + n) * 512 + l * 8);
        }
#pragma unroll
    for (int kb = 0; kb < 4; ++kb)
#pragma unroll
        for (int n = 0; n < 2; ++n)
            wn[kb][n] = *(const h8*)(pW + OFF_NODE + (size_t)(kb * 16 + w * 2 + n) * 512 + l * 8);

    float breg[2];
#pragma unroll
    for (int n = 0; n < 2; ++n) breg[n] = bB[w * 32 + n * 16 + lm];

    const int NT = (NN + 31) / 32;
    f4 pXa, pXb;
    int4 p1[2];
    int t = blockIdx.x;
    {
        int grow = t * 32 + rx;
        const f4 zf = {0.f, 0.f, 0.f, 0.f};
        pXa = (grow < NN) ? *(const f4*)(x + (size_t)grow * FF + sx * 8) : zf;
        pXb = (grow < NN) ? *(const f4*)(x + (size_t)grow * FF + sx * 8 + 4) : zf;
#pragma unroll
        for (int j = 0; j < 2; ++j) {
            int unit = tid * 2 + j;
            int r = unit >> 5, s = unit & 31;
            int g2 = t * 32 + r;
            int4 z = {0, 0, 0, 0};
            p1[j] = (g2 < NN) ? *(const int4*)(A1 + (size_t)g2 * HH + s * 8) : z;
        }
    }

    for (; t < NT; t += gridDim.x) {
        __syncthreads();  // b0: previous tile's compute fully done
        {
            h8 hx;
            hx[0] = (_Float16)pXa[0]; hx[1] = (_Float16)pXa[1];
            hx[2] = (_Float16)pXa[2]; hx[3] = (_Float16)pXa[3];
            hx[4] = (_Float16)pXb[0]; hx[5] = (_Float16)pXb[1];
            hx[6] = (_Float16)pXb[2]; hx[7] = (_Float16)pXb[3];
            *(int4*)(sm + rx * 256 + SWZ(rx, sx * 16)) = *(int4*)&hx;
        }
#pragma unroll
        for (int j = 0; j < 2; ++j) {
            int unit = tid * 2 + j;
            int r = unit >> 5, s = unit & 31;
            *(int4*)(sm + 8192 + r * 512 + SWZ(r, s * 16)) = p1[j];
        }
        int tn = t + gridDim.x;
        if (tn < NT) {
            int grow = tn * 32 + rx;
            const f4 zf = {0.f, 0.f, 0.f, 0.f};
            pXa = (grow < NN) ? *(const f4*)(x + (size_t)grow * FF + sx * 8) : zf;
            pXb = (grow < NN) ? *(const f4*)(x + (size_t)grow * FF + sx * 8 + 4) : zf;
#pragma unroll
            for (int j = 0; j < 2; ++j) {
                int unit = tid * 2 + j;
                int r = unit >> 5, s = unit & 31;
                int g2 = tn * 32 + r;
                int4 z = {0, 0, 0, 0};
                p1[j] = (g2 < NN) ? *(const int4*)(A1 + (size_t)g2 * HH + s * 8) : z;
            }
        }
        __syncthreads();  // b1: sX, sA1 ready

        // ---- hx0 = x @ W_node for this wave's 32 cols -> sHX
        {
            f4 acch[2][2];
            const f4 z4 = {0.f, 0.f, 0.f, 0.f};
#pragma unroll
            for (int rf = 0; rf < 2; ++rf)
#pragma unroll
                for (int n = 0; n < 2; ++n) acch[rf][n] = z4;
#pragma unroll
            for (int kb = 0; kb < 4; ++kb) {
                h8 a0 = *(const h8*)(sm + lm * 256 + SWZ(lm, kb * 64 + lg * 16));
                h8 a1 = *(const h8*)(sm + (16 + lm) * 256 + SWZ(16 + lm, kb * 64 + lg * 16));
#pragma unroll
                for (int n = 0; n < 2; ++n) {
                    acch[0][n] = __builtin_amdgcn_mfma_f32_16x16x32_f16(a0, wn[kb][n], acch[0][n], 0, 0, 0);
                    acch[1][n] = __builtin_amdgcn_mfma_f32_16x16x32_f16(a1, wn[kb][n], acch[1][n], 0, 0, 0);
                }
            }
#pragma unroll
            for (int rf = 0; rf < 2; ++rf)
#pragma unroll
                for (int n = 0; n < 2; ++n) {
                    int c2 = (w * 32 + n * 16 + lm) * 2;
#pragma unroll
                    for (int q = 0; q < 4; ++q) {
                        int r = rf * 16 + lg * 4 + q;
                        *(_Float16*)(sm + 24576 + r * 512 + SWZ(r, c2)) = (_Float16)acch[rf][n][q];
                    }
                }
        }
        __syncthreads();  // b2: sHX ready

        f4 acc[2][2];
        const f4 z4 = {0.f, 0.f, 0.f, 0.f};
#pragma unroll
        for (int rf = 0; rf < 2; ++rf)
#pragma unroll
            for (int n = 0; n < 2; ++n) acc[rf][n] = z4;

#pragma unroll
        for (int kb = 0; kb < 8; ++kb) {
            h8 a10 = *(const h8*)(sm + 8192 + lm * 512 + SWZ(lm, kb * 64 + lg * 16));
            h8 a11 = *(const h8*)(sm + 8192 + (16 + lm) * 512 + SWZ(16 + lm, kb * 64 + lg * 16));
            h8 a20 = *(const h8*)(sm + 24576 + lm * 512 + SWZ(lm, kb * 64 + lg * 16));
            h8 a21 = *(const h8*)(sm + 24576 + (16 + lm) * 512 + SWZ(16 + lm, kb * 64 + lg * 16));
#pragma unroll
            for (int n = 0; n < 2; ++n) {
                acc[0][n] = __builtin_amdgcn_mfma_f32_16x16x32_f16(a10, w1[kb][n], acc[0][n], 0, 0, 0);
                acc[1][n] = __builtin_amdgcn_mfma_f32_16x16x32_f16(a11, w1[kb][n], acc[1][n], 0, 0, 0);
                acc[0][n] = __builtin_amdgcn_mfma_f32_16x16x32_f16(a20, w2[kb][n], acc[0][n], 0, 0, 0);
                acc[1][n] = __builtin_amdgcn_mfma_f32_16x16x32_f16(a21, w2[kb][n], acc[1][n], 0, 0, 0);
            }
        }

        const int row0 = t * 32;
#pragma unroll
        for (int rf = 0; rf < 2; ++rf)
#pragma unroll
            for (int n = 0; n < 2; ++n) {
                const int col = w * 32 + n * 16 + lm;
#pragma unroll
                for (int q = 0; q < 4; ++q) {
                    int grow = row0 + rf * 16 + lg * 4 + q;
                    if (grow < NN) {
                        float v = fmaxf(acc[rf][n][q] + breg[n], 0.f);
                        C[(size_t)grow * HH + col] = (_Float16)v;
                    }
                }
            }
    }
}

// ---------------- BN fold + pack final weights into MFMA-B fragments ----------------
__global__ __launch_bounds__(256)
void k_bnprep(const float* __restrict__ stats, const float* __restrict__ gamma,
              const float* __restrict__ beta, const float* __restrict__ W_f2,
              const float* __restrict__ b_f2, _Float16* __restrict__ pWf,
              float* __restrict__ bfold) {
    __shared__ float sh[HH];
    __shared__ float ssc[HH];
    const int tid = threadIdx.x;
    const float invN = 1.0f / (float)NN;
    {
        float mu = stats[tid] * invN;
        float var = stats[HH + tid] * invN - mu * mu;
        float scale = gamma[tid] * rsqrtf(var + BN_EPS);
        sh[tid] = beta[tid] - mu * scale;
        ssc[tid] = scale;
    }
    __syncthreads();
    if (tid < CC) {
        float b = b_f2[tid];
        for (int k = 0; k < HH; ++k) b += sh[k] * W_f2[k * CC + tid];
        bfold[tid] = b;
    }
    const int w = tid >> 6, l = tid & 63;
    const int lm = l & 15, lg = l >> 4;
#pragma unroll
    for (int i = 0; i < 6; ++i) {
        int u = w + i * 4;  // 0..23
        int kb = u / 3, nb = u % 3;
        h8 hv;
#pragma unroll
        for (int j = 0; j < 8; ++j) {
            int k = kb * 32 + lg * 8 + j;
            int c = nb * 16 + lm;
            float v = (c < CC) ? ssc[k] * W_f2[k * CC + c] : 0.f;
            hv[j] = (_Float16)v;
        }
        *(h8*)(pWf + (size_t)u * 512 + l * 8) = hv;
    }
}

// ---------------- final via MFMA: out = h @ (scale*W_f2) + bfold ----------------
__global__ __launch_bounds__(256)
void k_finalM(const _Float16* __restrict__ h, const _Float16* __restrict__ pWf,
              const float* __restrict__ bfold, float* __restrict__ out) {
    __shared__ __align__(16) char sA[64 * 512];
    const int tid = threadIdx.x;
    const int w = tid >> 6, l = tid & 63;
    const int lm = l & 15, lg = l >> 4;

    h8 wreg[8][3];
#pragma unroll
    for (int kb = 0; kb < 8; ++kb)
#pragma unroll
        for (int nb = 0; nb < 3; ++nb)
            wreg[kb][nb] = *(const h8*)(pWf + (size_t)(kb * 3 + nb) * 512 + l * 8);

    const int row0 = blockIdx.x * 64;
#pragma unroll
    for (int j = 0; j < 8; ++j) {
        int unit = tid * 8 + j;
        int r = unit >> 5, s = unit & 31;
        int grow = row0 + r;
        int4 z = {0, 0, 0, 0};
        int4 v = (grow < NN) ? *(const int4*)(h + (size_t)grow * HH + s * 8) : z;
        *(int4*)(sA + r * 512 + SWZ(r, s * 16)) = v;
    }
    __syncthreads();

    f4 acc[3];
    const f4 z4 = {0.f, 0.f, 0.f, 0.f};
#pragma unroll
    for (int nb = 0; nb < 3; ++nb) acc[nb] = z4;

    const int ar = w * 16 + lm;
#pragma unroll
    for (int kb = 0; kb < 8; ++kb) {
        h8 a = *(const h8*)(sA + ar * 512 + SWZ(ar, kb * 64 + lg * 16));
#pragma unroll
        for (int nb = 0; nb < 3; ++nb)
            acc[nb] = __builtin_amdgcn_mfma_f32_16x16x32_f16(a, wreg[kb][nb], acc[nb], 0, 0, 0);
    }

#pragma unroll
    for (int nb = 0; nb < 3; ++nb) {
        int col = nb * 16 + lm;
        if (col < CC) {
            float bb = bfold[col];
#pragma unroll
            for (int q = 0; q < 4; ++q) {
                int grow = row0 + w * 16 + lg * 4 + q;
                if (grow < NN) out[(size_t)grow * CC + col] = acc[nb][q] + bb;
            }
        }
    }
}

extern "C" void kernel_launch(void* const* d_in, const int* in_sizes, int n_in,
                              void* d_out, int out_size, void* d_ws, size_t ws_size,
                              hipStream_t stream) {
    const float* x      = (const float*)d_in[0];
    const int*   ei     = (const int*)d_in[1];
    const float* ew     = (const float*)d_in[2];
    const float* W_edge = (const float*)d_in[3];
    const float* b_edge = (const float*)d_in[4];
    const float* W_node = (const float*)d_in[5];
    const float* b_node = (const float*)d_in[6];
    const float* W_c1   = (const float*)d_in[7];
    const float* b_c1   = (const float*)d_in[8];
    const float* W_c2   = (const float*)d_in[9];
    const float* b_c2   = (const float*)d_in[10];
    const float* W_f1   = (const float*)d_in[11];
    const float* b_f1   = (const float*)d_in[12];
    const float* gamma  = (const float*)d_in[13];
    const float* beta   = (const float*)d_in[14];
    const float* W_f2   = (const float*)d_in[15];
    const float* b_f2   = (const float*)d_in[16];
    float* out = (float*)d_out;

    const size_t NNH = (size_t)NN * HH;
    _Float16* bufA = (_Float16*)d_ws;            // h_a -> outB (in place)
    _Float16* bufH = bufA + NNH;                 // h
    _Float16* W16  = bufH + NNH;                 // fp16 W_edge
    int2* esw      = (int2*)(W16 + NNH);         // E pairs
    float* stats   = (float*)(esw + EE);         // 512
    float* bB      = stats + 2 * HH;             // 256
    float* bfold   = bB + HH;                    // 64
    _Float16* pWf  = (_Float16*)(bfold + 64);    // 24*512
    _Float16* pW   = pWf + 24 * 512;             // PW_HALVES
    int* deg       = (int*)(pW + PW_HALVES);     // N
    int* rowptr    = deg + NN;                   // N+1
    int* pos       = rowptr + NN + 1;            // N
    int* bsums     = pos + NN;                   // 256

    k_init<<<196, 256, 0, stream>>>(stats, deg);
    k_prep<<<2048, 256, 0, stream>>>(W_edge, W16, ei, deg);
    k_pack<<<113, 256, 0, stream>>>(W_node, W_c1, W_c2, W_f1, b_node, b_c1, b_c2, pW, bB);
    k_scan1<<<196, 256, 0, stream>>>(deg, rowptr, bsums);
    k_scan2<<<1, 256, 0, stream>>>(bsums);
    k_scan3<<<196, 256, 0, stream>>>(rowptr, bsums, pos);
    k_ssort<<<(EE + 255) / 256, 256, 0, stream>>>(ei, ew, pos, esw);
    k_gather<<<12500, 256, 0, stream>>>(rowptr, esw, W16, b_edge, bufA);

    // GB2: outB = relu(h_a@(I+Wc1) + (x@Wn)@(I+Wc2) + bB) -> bufA (in place)
    k_gemmB2<<<256, 512, 0, stream>>>(x, bufA, pW, bB, bufA);
    // GC: h = relu(outB @ W_f1 + b_f1) + BN stats -> bufH
    k_gemm<8, 1><<<512, 256, 0, stream>>>(bufA, pW + OFF_F1, b_f1, bufH, stats);

    k_bnprep<<<1, 256, 0, stream>>>(stats, gamma, beta, W_f2, b_f2, pWf, bfold);
    k_finalM<<<(NN + 63) / 64, 256, 0, stream>>>(bufH, pWf, bfold, out);
}